// Round 7
// baseline (899.471 us; speedup 1.0000x reference)
//
#include <hip/hip_runtime.h>
#include <hip/hip_bf16.h>

typedef __hip_bfloat16 bf16;
typedef __attribute__((ext_vector_type(8))) short s8v;   // 8 bf16 (16B)
typedef __attribute__((ext_vector_type(4))) float f4v;   // 4 f32 (C/D frag)

// Branch-free erf (A&S 7.1.26), |err| < 1.5e-7 — exact at bf16 resolution.
__device__ __forceinline__ float erf_approx(float x) {
    float ax = fabsf(x);
    float t = 1.0f / (1.0f + 0.3275911f * ax);
    float p = t * (0.254829592f + t * (-0.284496736f + t * (1.421413741f
              + t * (-1.453152027f + t * 1.061405429f))));
    float r = 1.0f - p * __expf(-ax * ax);
    return copysignf(r, x);
}
__device__ __forceinline__ float gelu_f(float v) {
    return 0.5f * v * (1.f + erf_approx(v * 0.70710678118654752440f));
}
__device__ __forceinline__ unsigned short f2bf_u(float f) {
    bf16 b = __float2bfloat16(f);
    return *(unsigned short*)&b;
}
__device__ __forceinline__ float bfu2f(unsigned short u) {
    bf16 b = *(bf16*)&u;
    return __bfloat162float(b);
}

// ---------------------------------------------------------------------------
__global__ __launch_bounds__(256) void zero_k(float* __restrict__ p, int n) {
    int i = blockIdx.x * 256 + threadIdx.x;
    if (i < n) p[i] = 0.f;
}

// ---------------------------------------------------------------------------
// Convert + K-PERMUTE conv weights W1..W5 fp32 -> bf16.
// Wp[co][kc*64 + s*32 + ci_l] = W[co][kc*32+ci_l][s]  (kc<8, s<2, ci_l<32)
// ---------------------------------------------------------------------------
__global__ __launch_bounds__(256) void wcvt_k(
    const float* __restrict__ w1, const float* __restrict__ w2,
    const float* __restrict__ w3, const float* __restrict__ w4,
    const float* __restrict__ w5, bf16* __restrict__ dst)
{
    int i = blockIdx.x * 256 + threadIdx.x;
    if (i >= 557056) return;
    const float* src; int li;
    if      (i < 131072) { src = w1; li = i; }
    else if (i < 262144) { src = w2; li = i - 131072; }
    else if (i < 393216) { src = w3; li = i - 262144; }
    else if (i < 524288) { src = w4; li = i - 393216; }
    else                 { src = w5; li = i - 524288; }
    int co = li >> 9, rem = li & 511;
    int kc = rem >> 6, rr = rem & 63;
    int s = rr >> 5, cil = rr & 31;
    dst[i] = __float2bfloat16(src[co * 512 + (kc * 32 + cil) * 2 + s]);
}

// ---------------------------------------------------------------------------
// conv0 channel-collapse coefficients (sum over co of v and v^2 as a
// quadratic form in (x0,x1,x2,1)).
// ---------------------------------------------------------------------------
__global__ __launch_bounds__(256) void m0red_k(
    const float* __restrict__ W0, const float* __restrict__ b0, float* __restrict__ coef)
{
    __shared__ float red[256];
    const int co = threadIdx.x;
    float w0 = W0[3 * co], w1 = W0[3 * co + 1], w2 = W0[3 * co + 2], b = b0[co];
    float vals[14] = {w0, w1, w2, b,
                      w0 * w0, w1 * w1, w2 * w2, b * b,
                      2.f * w0 * w1, 2.f * w0 * w2, 2.f * w1 * w2,
                      2.f * w0 * b, 2.f * w1 * b, 2.f * w2 * b};
    for (int k = 0; k < 14; k++) {
        red[co] = vals[k];
        __syncthreads();
        for (int st = 128; st > 0; st >>= 1) {
            if (co < st) red[co] += red[co + st];
            __syncthreads();
        }
        if (co == 0) coef[k] = red[0];
        __syncthreads();
    }
}

// ---------------------------------------------------------------------------
// GN0 stats per node via the collapsed quadratic form. One block per node.
// ---------------------------------------------------------------------------
__global__ __launch_bounds__(256) void c0stats_k(
    const float* __restrict__ x, const float* __restrict__ coef,
    float* __restrict__ mu0, float* __restrict__ rstd0)
{
    __shared__ float xsl[3008];
    __shared__ float red[512];
    const int n = blockIdx.x, tid = threadIdx.x;
    const float* xr = x + (size_t)n * 3000;
    for (int i = tid; i < 750; i += 256) *(float4*)&xsl[4 + 4 * i] = *(const float4*)(xr + 4 * i);
    if (tid < 4) xsl[tid] = 0.f;
    float c[14];
    #pragma unroll
    for (int k = 0; k < 14; k++) c[k] = coef[k];
    __syncthreads();
    float S = 0.f, Q = 0.f;
    if (tid < 250) {
        float f[16];
        #pragma unroll
        for (int k = 0; k < 4; k++) *(float4*)&f[4 * k] = *(const float4*)&xsl[12 * tid + 4 * k];
        #pragma unroll
        for (int j = 0; j < 4; j++) {
            float x0 = f[3 * j + 3], x1 = f[3 * j + 4], x2 = f[3 * j + 5];
            S += c[0] * x0 + c[1] * x1 + c[2] * x2 + c[3];
            Q += c[4] * x0 * x0 + c[5] * x1 * x1 + c[6] * x2 * x2 + c[7]
               + c[8] * x0 * x1 + c[9] * x0 * x2 + c[10] * x1 * x2
               + c[11] * x0 + c[12] * x1 + c[13] * x2;
        }
    }
    red[tid] = S; red[256 + tid] = Q;
    __syncthreads();
    for (int st = 128; st > 0; st >>= 1) {
        if (tid < st) { red[tid] += red[tid + st]; red[256 + tid] += red[256 + tid + st]; }
        __syncthreads();
    }
    if (tid == 0) {
        float m = red[0] * (1.f / 256000.f);
        float var = red[256] * (1.f / 256000.f) - m * m;
        mu0[n] = m;
        rstd0[n] = rsqrtf(var + 1e-5f);
    }
}

// ---------------------------------------------------------------------------
// h0gT[z][t][ci] = gelu(gn0(conv0(x))) bf16, TRANSPOSED layout, node-chunked.
// ---------------------------------------------------------------------------
__global__ __launch_bounds__(256) void h0gT_k(
    const float* __restrict__ x, const float* __restrict__ W0,
    const float* __restrict__ b0, const float* __restrict__ g0,
    const float* __restrict__ be0, const float* __restrict__ mu0,
    const float* __restrict__ rstd0, bf16* __restrict__ h0gT, int n0)
{
    __shared__ float xs[96];
    __shared__ float w0s[768];
    __shared__ float aco[256], cco[256];
    const int z = blockIdx.y;
    const int n = n0 + z;
    const int t0 = blockIdx.x * 32;
    const int tid = threadIdx.x;
    for (int i = tid; i < 768; i += 256) w0s[i] = W0[i];
    {
        float mu = mu0[n], rs = rstd0[n];
        float a = rs * g0[tid];
        aco[tid] = a;
        cco[tid] = (b0[tid] - mu) * a + be0[tid];
    }
    if (tid < 96) {
        int xg = 3 * t0 - 1 + tid;
        xs[tid] = (xg >= 0 && xg < 3000) ? x[(size_t)n * 3000 + xg] : 0.f;
    }
    __syncthreads();
    const int oct = tid & 31, ci0 = oct * 8;
    const int tq = tid >> 5;
    #pragma unroll
    for (int u = 0; u < 4; u++) {
        int tl = tq + 8 * u;
        int t = t0 + tl;
        if (t >= 1000) continue;
        float x0 = xs[3 * tl], x1 = xs[3 * tl + 1], x2 = xs[3 * tl + 2];
        ushort4 lo, hi;
        unsigned short* pu = (unsigned short*)&lo;
        #pragma unroll
        for (int jj = 0; jj < 8; jj++) {
            int ci = ci0 + jj;
            float conv = w0s[3 * ci] * x0 + w0s[3 * ci + 1] * x1 + w0s[3 * ci + 2] * x2;
            float v = gelu_f(conv * aco[ci] + cco[ci]);
            if (jj < 4) pu[jj] = f2bf_u(v);
            else ((unsigned short*)&hi)[jj - 4] = f2bf_u(v);
        }
        bf16* orow = h0gT + ((size_t)z * 1000 + t) * 256 + ci0;
        *(ushort4*)orow = lo;
        *(ushort4*)(orow + 4) = hi;
    }
}

// ===========================================================================
// DOUBLE-BUFFERED single-barrier MFMA conv GEMM + optional fused GN+GELU.
// Per kc iteration:
//   1. issue staging GLOBAL LOADS for kc+1 (latency hides under step 3)
//   2. B-fragment loads for kc (L2-resident weights)
//   3. ds_read A-frags from buf[kc&1] + MFMAs  (matrix pipe)
//   4. gelu/GN on staged values (VALU pipe, overlaps step 3's matrix work)
//      + swizzled ds_write into buf[(kc+1)&1]
//   5. ONE __syncthreads()  (reads of buf[kc&1] all precede it; writes
//      target the other buffer -> single barrier is sufficient)
// R6 BUG FIXED: "slot invalid" (thread has no slot, only when NSLOT%256!=0)
// is now a separate flag s_inv[u], NOT the sentinel tin==-1 — tin==-1 is the
// legitimate left conv-pad row, which must WRITE ZEROS (R6 skipped it,
// leaving garbage/stale LDS for layer 5's pad slots).
// ===========================================================================
template<int MW, int NW, bool FUSE>
__global__ __launch_bounds__(256) void convT_k(
    const bf16* __restrict__ g, const bf16* __restrict__ Wp,
    const float* __restrict__ bias, bf16* __restrict__ hout,
    float* __restrict__ ssum, float* __restrict__ ssq,
    int T_g, int T_out, int n0,
    const float* __restrict__ pssum, const float* __restrict__ pssq,
    const float* __restrict__ pgam, const float* __restrict__ pbet,
    float pinvCT)
{
    constexpr int CO = 4 * NW * 16;
    constexpr int MT = MW * 16;
    constexpr int NSLOT = MT * 8;          // 16B slots in the A tile per chunk
    constexpr int NU = (NSLOT + 255) / 256;
    __shared__ bf16 aT[2][MT * 64];        // double-buffered swizzled A tile
    __shared__ float biasS[CO];
    __shared__ float red[512];
    __shared__ float acoS[256], ccoS[256];
    const int n  = blockIdx.y;
    const int t0 = blockIdx.x * MT;
    const int tid = threadIdx.x;
    for (int i = tid; i < CO; i += 256) biasS[i] = bias[i];
    if (FUSE) {
        float mu = pssum[n0 + n] * pinvCT;
        float rs = rsqrtf(pssq[n0 + n] * pinvCT - mu * mu + 1e-5f);
        float a = rs * pgam[tid];
        acoS[tid] = a;
        ccoS[tid] = pbet[tid] - mu * a;
    }
    const int w = tid >> 6, lane = tid & 63;
    const int l16 = lane & 15, quad = lane >> 4;
    const int sx = l16 & 7;                // read-side swizzle key (row & 7)
    const bf16* gb = g + (size_t)n * T_g * 256;

    // Per-thread staging slot geometry (kc-independent).
    // s_inv: thread's u-th slot doesn't exist (only possible if NSLOT%256!=0).
    // s_tin may be -1 (natural left pad) or >=T_g (right pad): stage ZEROS.
    bool s_inv[NU];
    int s_q[NU], s_tin[NU], s_off[NU];
    #pragma unroll
    for (int u = 0; u < NU; u++) {
        int slot = tid + 256 * u;
        s_inv[u] = (NSLOT % 256 != 0) && (slot >= NSLOT);
        if (s_inv[u]) { s_tin[u] = 0x7fffffff; s_q[u] = 0; s_off[u] = 0; continue; }
        int t = slot >> 3, j = slot & 7;
        int ks = j >> 2, q = j & 3;
        s_q[u] = q;
        s_tin[u] = 2 * (t0 + t) - 1 + ks;
        s_off[u] = (t * 8 + (j ^ (t & 7))) * 8;   // swizzled LDS elem offset
    }

    f4v acc[MW][NW];
    #pragma unroll
    for (int i = 0; i < MW; i++)
        #pragma unroll
        for (int j = 0; j < NW; j++) acc[i][j] = (f4v){0.f, 0.f, 0.f, 0.f};

    // FUSE: acoS/ccoS must be visible before first gelu use.
    if (FUSE) __syncthreads();

    // ---- prologue: fully stage kc=0 into aT[0] (OOB rows -> zeros)
    #pragma unroll
    for (int u = 0; u < NU; u++) {
        if (s_inv[u]) continue;
        int tin = s_tin[u];
        s8v v = (s8v){0, 0, 0, 0, 0, 0, 0, 0};
        if ((unsigned)tin < (unsigned)T_g) {
            v = *(const s8v*)(gb + (size_t)tin * 256 + s_q[u] * 8);
            if (FUSE) {
                const int ci0 = s_q[u] * 8;
                unsigned short* uu = (unsigned short*)&v;
                #pragma unroll
                for (int jj = 0; jj < 8; jj++)
                    uu[jj] = f2bf_u(gelu_f(bfu2f(uu[jj]) * acoS[ci0 + jj] + ccoS[ci0 + jj]));
            }
        }
        *(s8v*)&aT[0][s_off[u]] = v;
    }
    __syncthreads();

    #pragma unroll 2
    for (int kc = 0; kc < 8; kc++) {
        const int kn = kc + 1;
        // ---- 1. issue staging loads for kc+1 (consumed in step 4)
        s8v vst[NU]; int vok[NU];
        #pragma unroll
        for (int u = 0; u < NU; u++) {
            vst[u] = (s8v){0, 0, 0, 0, 0, 0, 0, 0};
            vok[u] = 0;
            if (kn < 8 && !s_inv[u] && (unsigned)s_tin[u] < (unsigned)T_g) {
                vst[u] = *(const s8v*)(gb + (size_t)s_tin[u] * 256 + kn * 32 + s_q[u] * 8);
                vok[u] = 1;
            }
        }
        // ---- 2. B fragments for kc
        s8v bfr[2][NW];
        #pragma unroll
        for (int ks = 0; ks < 2; ks++)
            #pragma unroll
            for (int j = 0; j < NW; j++) {
                int co = w * NW * 16 + j * 16 + l16;
                bfr[ks][j] = *(const s8v*)(Wp + (size_t)co * 512 + kc * 64 + ks * 32 + quad * 8);
            }
        // ---- 3. ds_read + MFMA on buf[kc&1]
        const bf16* rb = aT[kc & 1];
        #pragma unroll
        for (int ks = 0; ks < 2; ks++) {
            const int sl = (ks * 4 + quad) ^ sx;   // swizzled 16B slot
            s8v af[MW];
            #pragma unroll
            for (int i = 0; i < MW; i++)
                af[i] = *(const s8v*)&rb[(i * 16 + l16) * 64 + sl * 8];
            #pragma unroll
            for (int i = 0; i < MW; i++)
                #pragma unroll
                for (int j = 0; j < NW; j++)
                    acc[i][j] = __builtin_amdgcn_mfma_f32_16x16x32_bf16(af[i], bfr[ks][j], acc[i][j], 0, 0, 0);
        }
        // ---- 4. activation + ds_write of kc+1 into buf[kn&1] (zeros for pad)
        if (kn < 8) {
            bf16* wb = aT[kn & 1];
            #pragma unroll
            for (int u = 0; u < NU; u++) {
                if (s_inv[u]) continue;
                s8v v = vst[u];
                if (FUSE && vok[u]) {
                    const int ci0 = kn * 32 + s_q[u] * 8;
                    unsigned short* uu = (unsigned short*)&v;
                    #pragma unroll
                    for (int jj = 0; jj < 8; jj++)
                        uu[jj] = f2bf_u(gelu_f(bfu2f(uu[jj]) * acoS[ci0 + jj] + ccoS[ci0 + jj]));
                }
                *(s8v*)&wb[s_off[u]] = v;
            }
            // ---- 5. single barrier per kc
            __syncthreads();
        }
    }

    float lsum = 0.f, lsq = 0.f;
    #pragma unroll
    for (int i = 0; i < MW; i++) {
        #pragma unroll
        for (int r = 0; r < 4; r++) {
            int t = t0 + i * 16 + quad * 4 + r;
            if (t < T_out) {
                bf16* orow = hout + ((size_t)n * T_out + t) * CO;
                #pragma unroll
                for (int j = 0; j < NW; j++) {
                    int co = w * NW * 16 + j * 16 + l16;
                    float v = acc[i][j][r] + biasS[co];
                    orow[co] = __float2bfloat16(v);
                    lsum += v; lsq += v * v;
                }
            }
        }
    }
    red[tid] = lsum; red[256 + tid] = lsq;
    __syncthreads();
    for (int st = 128; st > 0; st >>= 1) {
        if (tid < st) { red[tid] += red[tid + st]; red[256 + tid] += red[256 + tid + st]; }
        __syncthreads();
    }
    if (tid == 0) { atomicAdd(&ssum[n0 + n], red[0]); atomicAdd(&ssq[n0 + n], red[256]); }
}

// ---------------------------------------------------------------------------
// Tail kernel 1: GN5+GELU on h5T[n][t][c] + readout 1x1 + msg round-0 pre.
// ---------------------------------------------------------------------------
__global__ __launch_bounds__(256) void readout_pre_k(
    const bf16* __restrict__ h5T, const float* __restrict__ row,
    const float* __restrict__ rob, const float* __restrict__ g5,
    const float* __restrict__ be5, const float* __restrict__ ssum,
    const float* __restrict__ ssq, float invCT,
    const float* __restrict__ mw, const float* __restrict__ mb,
    float* __restrict__ lat0, float* __restrict__ A0, float* __restrict__ Bv0)
{
    __shared__ float lh[2112];   // [t][c] 33 x 64
    __shared__ float ll[2112];   // lat [t][d]
    __shared__ float lw[8192];
    __shared__ float lb[64];
    const int n = blockIdx.x, tid = threadIdx.x;
    const float mu = ssum[n] * invCT;
    const float rs = rsqrtf(ssq[n] * invCT - mu * mu + 1e-5f);
    for (int idx = tid; idx < 2112; idx += 256) {
        int c = idx & 63;
        float a = rs * g5[c];
        float v = __bfloat162float(h5T[(size_t)n * 2112 + idx]) * a + (be5[c] - mu * a);
        lh[idx] = gelu_f(v);
    }
    for (int idx = tid; idx < 4096; idx += 256) lw[idx] = row[idx];
    if (tid < 64) lb[tid] = rob[tid];
    __syncthreads();
    for (int idx = tid; idx < 2112; idx += 256) {
        int t = idx >> 6, d = idx & 63;
        float a = lb[d];
        #pragma unroll 8
        for (int c = 0; c < 64; c++) a += lh[t * 64 + c] * lw[c * 64 + d];
        ll[idx] = a;
        lat0[(size_t)n * 2112 + idx] = a;
    }
    __syncthreads();
    for (int idx = tid; idx < 8192; idx += 256) lw[idx] = mw[idx];
    if (tid < 64) lb[tid] = mb[tid];
    __syncthreads();
    for (int idx = tid; idx < 2112; idx += 256) {
        int t = idx >> 6, d = idx & 63;
        float a = 0.f, bb = lb[d];
        #pragma unroll 8
        for (int k = 0; k < 64; k++) {
            float xv = ll[t * 64 + k];
            a  += xv * lw[k * 64 + d];
            bb += xv * lw[(64 + k) * 64 + d];
        }
        A0[(size_t)n * 2112 + idx]  = a;
        Bv0[(size_t)n * 2112 + idx] = bb;
    }
}

// ---------------------------------------------------------------------------
// Tail kernel 2: msg round-0 combine + msg round-1 pre.
// ---------------------------------------------------------------------------
__global__ __launch_bounds__(256) void comb_pre_k(
    const float* __restrict__ lat0, const float* __restrict__ A0,
    const float* __restrict__ Bv0, const float* __restrict__ mw,
    const float* __restrict__ mb, float* __restrict__ lat1,
    float* __restrict__ A1, float* __restrict__ Bv1)
{
    __shared__ float ll[2112];
    __shared__ float lw[8192];
    __shared__ float lb[64];
    const int n = blockIdx.x, tid = threadIdx.x;
    const int b9 = (n / 9) * 9, j = n - b9;
    for (int idx = tid; idx < 2112; idx += 256) {
        float base = Bv0[(size_t)n * 2112 + idx];
        float s = 0.f;
        #pragma unroll
        for (int i = 0; i < 9; i++) {
            if (i == j) continue;
            s += fmaxf(A0[(size_t)(b9 + i) * 2112 + idx] + base, 0.f);
        }
        float v = lat0[(size_t)n * 2112 + idx] + s * 0.125f;
        ll[idx] = v;
        lat1[(size_t)n * 2112 + idx] = v;
    }
    for (int idx = tid; idx < 8192; idx += 256) lw[idx] = mw[idx];
    if (tid < 64) lb[tid] = mb[tid];
    __syncthreads();
    for (int idx = tid; idx < 2112; idx += 256) {
        int t = idx >> 6, d = idx & 63;
        float a = 0.f, bb = lb[d];
        #pragma unroll 8
        for (int k = 0; k < 64; k++) {
            float xv = ll[t * 64 + k];
            a  += xv * lw[k * 64 + d];
            bb += xv * lw[(64 + k) * 64 + d];
        }
        A1[(size_t)n * 2112 + idx]  = a;
        Bv1[(size_t)n * 2112 + idx] = bb;
    }
}

// ---------------------------------------------------------------------------
// Tail kernel 3: msg round-1 combine + view-sum + readout MLP + projection.
// ---------------------------------------------------------------------------
__global__ __launch_bounds__(256) void final2_k(
    const float* __restrict__ lat1, const float* __restrict__ A1,
    const float* __restrict__ Bv1,
    const float* __restrict__ w1, const float* __restrict__ b1,
    const float* __restrict__ w2, const float* __restrict__ b2,
    const float* __restrict__ pw, const float* __restrict__ pb,
    float* __restrict__ out)
{
    __shared__ float ly[2112], lz[2112];
    __shared__ float lw1[4096], lw2[4096], lpw[2048];
    __shared__ float lb1[64], lb2[64], lpb[32];
    const int b = blockIdx.x, tid = threadIdx.x;
    for (int idx = tid; idx < 4096; idx += 256) { lw1[idx] = w1[idx]; lw2[idx] = w2[idx]; }
    for (int idx = tid; idx < 2048; idx += 256) lpw[idx] = pw[idx];
    if (tid < 64) { lb1[tid] = b1[tid]; lb2[tid] = b2[tid]; }
    if (tid < 32) lpb[tid] = pb[tid];
    for (int idx = tid; idx < 2112; idx += 256) {
        float Av[9], Bb[9], s = 0.f;
        #pragma unroll
        for (int jj = 0; jj < 9; jj++) {
            size_t off = ((size_t)(b * 9 + jj)) * 2112 + idx;
            Av[jj] = A1[off];
            Bb[jj] = Bv1[off];
            s += lat1[off];
        }
        float m = 0.f;
        #pragma unroll
        for (int jj = 0; jj < 9; jj++) {
            float rowsum = 0.f;
            #pragma unroll
            for (int ii = 0; ii < 9; ii++) rowsum += fmaxf(Av[ii] + Bb[jj], 0.f);
            m += rowsum - fmaxf(Av[jj] + Bb[jj], 0.f);
        }
        ly[idx] = s + m * 0.125f;
    }
    __syncthreads();
    for (int idx = tid; idx < 2112; idx += 256) {
        int t = idx >> 6, d = idx & 63;
        float s = lb1[d];
        #pragma unroll 8
        for (int k = 0; k < 64; k++) s += ly[t * 64 + k] * lw1[k * 64 + d];
        lz[idx] = fmaxf(s, 0.f);
    }
    __syncthreads();
    for (int idx = tid; idx < 2112; idx += 256) {
        int t = idx >> 6, d = idx & 63;
        float s = lb2[d];
        #pragma unroll 8
        for (int k = 0; k < 64; k++) s += lz[t * 64 + k] * lw2[k * 64 + d];
        ly[idx] = s * (1.f / 9.f);
    }
    __syncthreads();
    for (int idx = tid; idx < 1056; idx += 256) {
        int e = idx / 33, t = idx - e * 33;
        float s = lpb[e];
        #pragma unroll 8
        for (int d = 0; d < 64; d++) s += ly[t * 64 + d] * lpw[d * 32 + e];
        out[(size_t)b * 1056 + idx] = s;
    }
}

// ---------------------------------------------------------------------------
extern "C" void kernel_launch(void* const* d_in, const int* in_sizes, int n_in,
                              void* d_out, int out_size, void* d_ws, size_t ws_size,
                              hipStream_t stream)
{
    const float* x = (const float*)d_in[0];
    const float* cw[6]; const float* cb[6]; const float* gg[6]; const float* gb[6];
    for (int l = 0; l < 6; l++) {
        cw[l] = (const float*)d_in[1 + 4 * l];
        cb[l] = (const float*)d_in[2 + 4 * l];
        gg[l] = (const float*)d_in[3 + 4 * l];
        gb[l] = (const float*)d_in[4 + 4 * l];
    }
    const float* ro_w = (const float*)d_in[25];
    const float* ro_b = (const float*)d_in[26];
    const float* mw0  = (const float*)d_in[27];
    const float* mb0  = (const float*)d_in[28];
    const float* mw1  = (const float*)d_in[29];
    const float* mb1  = (const float*)d_in[30];
    const float* rw1  = (const float*)d_in[31];
    const float* rb1  = (const float*)d_in[32];
    const float* rw2  = (const float*)d_in[33];
    const float* rb2  = (const float*)d_in[34];
    const float* pw   = (const float*)d_in[35];
    const float* pb   = (const float*)d_in[36];

    // ---- workspace (ws_size = 268,435,456 B measured; peak ~260.1 MB) ----
    // All activation buffers TRANSPOSED: [n][t][ci]. h1..h4 stay RAW
    // (pre-GN); the consuming conv applies GN+GELU in its staging path.
    char* ws = (char*)d_ws;
    bf16* h1T  = (bf16*)(ws);                 // [576][501][256] 147,750,912 B
    bf16* h0gT = (bf16*)(ws + 147750912);     // [192][1000][256] 98,304,000 B (chunk)
    bf16* h2T  = (bf16*)(ws + 147750912);     // [576][251][256] (h0gT dead)
    bf16* h3T  = (bf16*)(ws + 221773824);     // [576][126][256] -> 258,932,736
    bf16* h4T  = (bf16*)(ws);                 // [576][64][256]  (h1T dead)
    bf16* h5T  = (bf16*)(ws + 147750912);     // [576][33][64]   (h2T dead)
    float* lat0 = (float*)(ws);               // 6 x 4,866,048 B (h4T dead after L5)
    float* A0   = lat0 + 1216512;
    float* Bv0  = A0   + 1216512;
    float* lat1 = Bv0  + 1216512;
    float* A1   = lat1 + 1216512;
    float* Bv1  = A1   + 1216512;
    float* stat  = (float*)(ws + 258932736);
    float* mu0   = stat;
    float* rstd0 = stat + 576;
    float* coef  = stat + 1152;               // 16
    float* ssumA = stat + 1168;               // 5 x 576
    float* ssqA  = ssumA + 5 * 576;
    bf16*  Wp    = (bf16*)(ws + 258965504);   // 557,056 bf16 -> 260,079,616
    #define SSUM(l) (ssumA + ((l) - 1) * 576)
    #define SSQ(l)  (ssqA  + ((l) - 1) * 576)

    zero_k<<<(5760 + 255) / 256, 256, 0, stream>>>(ssumA, 2 * 5 * 576);
    wcvt_k<<<(557056 + 255) / 256, 256, 0, stream>>>(cw[1], cw[2], cw[3], cw[4], cw[5], Wp);
    m0red_k<<<1, 256, 0, stream>>>(cw[0], cb[0], coef);
    c0stats_k<<<576, 256, 0, stream>>>(x, coef, mu0, rstd0);

    // ---- layer 1: h0gT (chunked x3) + GEMM (input already activated) ----
    for (int c = 0; c < 3; c++) {
        int n0 = c * 192;
        h0gT_k<<<dim3(32, 192), 256, 0, stream>>>(x, cw[0], cb[0], gg[0], gb[0], mu0, rstd0, h0gT, n0);
        convT_k<4, 4, false><<<dim3(8, 192), 256, 0, stream>>>(
            h0gT, Wp, cb[1], h1T + (size_t)n0 * 501 * 256, SSUM(1), SSQ(1), 1000, 501, n0,
            nullptr, nullptr, nullptr, nullptr, 0.f);
    }

    // ---- layer 2: fused GN1+GELU on raw h1T during staging ----
    convT_k<4, 4, true><<<dim3(4, 576), 256, 0, stream>>>(
        h1T, Wp + 131072, cb[2], h2T, SSUM(2), SSQ(2), 501, 251, 0,
        SSUM(1), SSQ(1), gg[1], gb[1], 1.f / (256.f * 501.f));

    // ---- layer 3: fused GN2+GELU ----
    convT_k<4, 4, true><<<dim3(2, 576), 256, 0, stream>>>(
        h2T, Wp + 262144, cb[3], h3T, SSUM(3), SSQ(3), 251, 126, 0,
        SSUM(2), SSQ(2), gg[2], gb[2], 1.f / (256.f * 251.f));

    // ---- layer 4: fused GN3+GELU ----
    convT_k<4, 4, true><<<dim3(1, 576), 256, 0, stream>>>(
        h3T, Wp + 393216, cb[4], h4T, SSUM(4), SSQ(4), 126, 64, 0,
        SSUM(3), SSQ(3), gg[3], gb[3], 1.f / (256.f * 126.f));

    // ---- layer 5 (CO=64): fused GN4+GELU ----
    convT_k<3, 1, true><<<dim3(1, 576), 256, 0, stream>>>(
        h4T, Wp + 524288, cb[5], h5T, SSUM(5), SSQ(5), 64, 33, 0,
        SSUM(4), SSQ(4), gg[4], gb[4], 1.f / (256.f * 64.f));

    // ---- fused tail: readout+pre0 -> comb0+pre1 -> comb1+sum+MLP+proj ----
    readout_pre_k<<<576, 256, 0, stream>>>(h5T, ro_w, ro_b, gg[5], gb[5],
                                           SSUM(5), SSQ(5), 1.f / (64.f * 33.f),
                                           mw0, mb0, lat0, A0, Bv0);
    comb_pre_k<<<576, 256, 0, stream>>>(lat0, A0, Bv0, mw1, mb1, lat1, A1, Bv1);
    final2_k<<<64, 256, 0, stream>>>(lat1, A1, Bv1, rw1, rb1, rw2, rb2, pw, pb, (float*)d_out);
}

// Round 8
// 857.267 us; speedup vs baseline: 1.0492x; 1.0492x over previous
//
#include <hip/hip_runtime.h>
#include <hip/hip_bf16.h>

typedef __hip_bfloat16 bf16;
typedef __attribute__((ext_vector_type(8))) short s8v;   // 8 bf16 (16B)
typedef __attribute__((ext_vector_type(4))) float f4v;   // 4 f32 (C/D frag)

// Branch-free erf (A&S 7.1.26), |err| < 1.5e-7 — exact at bf16 resolution.
// Uses HW v_rcp_f32 (1 trans op) instead of the IEEE divide expansion.
__device__ __forceinline__ float erf_approx(float x) {
    float ax = fabsf(x);
    float t = __builtin_amdgcn_rcpf(__builtin_fmaf(0.3275911f, ax, 1.0f));
    float p = t * (0.254829592f + t * (-0.284496736f + t * (1.421413741f
              + t * (-1.453152027f + t * 1.061405429f))));
    float r = 1.0f - p * __expf(-ax * ax);
    return copysignf(r, x);
}
__device__ __forceinline__ float gelu_f(float v) {
    return 0.5f * v * (1.f + erf_approx(v * 0.70710678118654752440f));
}
__device__ __forceinline__ unsigned short f2bf_u(float f) {
    bf16 b = __float2bfloat16(f);
    return *(unsigned short*)&b;
}
__device__ __forceinline__ float bfu2f(unsigned short u) {
    bf16 b = *(bf16*)&u;
    return __bfloat162float(b);
}

// ---------------------------------------------------------------------------
__global__ __launch_bounds__(256) void zero_k(float* __restrict__ p, int n) {
    int i = blockIdx.x * 256 + threadIdx.x;
    if (i < n) p[i] = 0.f;
}

// ---------------------------------------------------------------------------
// Convert + K-PERMUTE conv weights W1..W5 fp32 -> bf16.
// Wp[co][kc*64 + s*32 + ci_l] = W[co][kc*32+ci_l][s]  (kc<8, s<2, ci_l<32)
// ---------------------------------------------------------------------------
__global__ __launch_bounds__(256) void wcvt_k(
    const float* __restrict__ w1, const float* __restrict__ w2,
    const float* __restrict__ w3, const float* __restrict__ w4,
    const float* __restrict__ w5, bf16* __restrict__ dst)
{
    int i = blockIdx.x * 256 + threadIdx.x;
    if (i >= 557056) return;
    const float* src; int li;
    if      (i < 131072) { src = w1; li = i; }
    else if (i < 262144) { src = w2; li = i - 131072; }
    else if (i < 393216) { src = w3; li = i - 262144; }
    else if (i < 524288) { src = w4; li = i - 393216; }
    else                 { src = w5; li = i - 524288; }
    int co = li >> 9, rem = li & 511;
    int kc = rem >> 6, rr = rem & 63;
    int s = rr >> 5, cil = rr & 31;
    dst[i] = __float2bfloat16(src[co * 512 + (kc * 32 + cil) * 2 + s]);
}

// ---------------------------------------------------------------------------
// conv0 channel-collapse coefficients (sum over co of v and v^2 as a
// quadratic form in (x0,x1,x2,1)).
// ---------------------------------------------------------------------------
__global__ __launch_bounds__(256) void m0red_k(
    const float* __restrict__ W0, const float* __restrict__ b0, float* __restrict__ coef)
{
    __shared__ float red[256];
    const int co = threadIdx.x;
    float w0 = W0[3 * co], w1 = W0[3 * co + 1], w2 = W0[3 * co + 2], b = b0[co];
    float vals[14] = {w0, w1, w2, b,
                      w0 * w0, w1 * w1, w2 * w2, b * b,
                      2.f * w0 * w1, 2.f * w0 * w2, 2.f * w1 * w2,
                      2.f * w0 * b, 2.f * w1 * b, 2.f * w2 * b};
    for (int k = 0; k < 14; k++) {
        red[co] = vals[k];
        __syncthreads();
        for (int st = 128; st > 0; st >>= 1) {
            if (co < st) red[co] += red[co + st];
            __syncthreads();
        }
        if (co == 0) coef[k] = red[0];
        __syncthreads();
    }
}

// ---------------------------------------------------------------------------
// GN0 stats per node via the collapsed quadratic form. One block per node.
// ---------------------------------------------------------------------------
__global__ __launch_bounds__(256) void c0stats_k(
    const float* __restrict__ x, const float* __restrict__ coef,
    float* __restrict__ mu0, float* __restrict__ rstd0)
{
    __shared__ float xsl[3008];
    __shared__ float red[512];
    const int n = blockIdx.x, tid = threadIdx.x;
    const float* xr = x + (size_t)n * 3000;
    for (int i = tid; i < 750; i += 256) *(float4*)&xsl[4 + 4 * i] = *(const float4*)(xr + 4 * i);
    if (tid < 4) xsl[tid] = 0.f;
    float c[14];
    #pragma unroll
    for (int k = 0; k < 14; k++) c[k] = coef[k];
    __syncthreads();
    float S = 0.f, Q = 0.f;
    if (tid < 250) {
        float f[16];
        #pragma unroll
        for (int k = 0; k < 4; k++) *(float4*)&f[4 * k] = *(const float4*)&xsl[12 * tid + 4 * k];
        #pragma unroll
        for (int j = 0; j < 4; j++) {
            float x0 = f[3 * j + 3], x1 = f[3 * j + 4], x2 = f[3 * j + 5];
            S += c[0] * x0 + c[1] * x1 + c[2] * x2 + c[3];
            Q += c[4] * x0 * x0 + c[5] * x1 * x1 + c[6] * x2 * x2 + c[7]
               + c[8] * x0 * x1 + c[9] * x0 * x2 + c[10] * x1 * x2
               + c[11] * x0 + c[12] * x1 + c[13] * x2;
        }
    }
    red[tid] = S; red[256 + tid] = Q;
    __syncthreads();
    for (int st = 128; st > 0; st >>= 1) {
        if (tid < st) { red[tid] += red[tid + st]; red[256 + tid] += red[256 + tid + st]; }
        __syncthreads();
    }
    if (tid == 0) {
        float m = red[0] * (1.f / 256000.f);
        float var = red[256] * (1.f / 256000.f) - m * m;
        mu0[n] = m;
        rstd0[n] = rsqrtf(var + 1e-5f);
    }
}

// ---------------------------------------------------------------------------
// h0gT[z][t][ci] = gelu(gn0(conv0(x))) bf16, TRANSPOSED layout, node-chunked.
// ---------------------------------------------------------------------------
__global__ __launch_bounds__(256) void h0gT_k(
    const float* __restrict__ x, const float* __restrict__ W0,
    const float* __restrict__ b0, const float* __restrict__ g0,
    const float* __restrict__ be0, const float* __restrict__ mu0,
    const float* __restrict__ rstd0, bf16* __restrict__ h0gT, int n0)
{
    __shared__ float xs[96];
    __shared__ float w0s[768];
    __shared__ float aco[256], cco[256];
    const int z = blockIdx.y;
    const int n = n0 + z;
    const int t0 = blockIdx.x * 32;
    const int tid = threadIdx.x;
    for (int i = tid; i < 768; i += 256) w0s[i] = W0[i];
    {
        float mu = mu0[n], rs = rstd0[n];
        float a = rs * g0[tid];
        aco[tid] = a;
        cco[tid] = (b0[tid] - mu) * a + be0[tid];
    }
    if (tid < 96) {
        int xg = 3 * t0 - 1 + tid;
        xs[tid] = (xg >= 0 && xg < 3000) ? x[(size_t)n * 3000 + xg] : 0.f;
    }
    __syncthreads();
    const int oct = tid & 31, ci0 = oct * 8;
    const int tq = tid >> 5;
    #pragma unroll
    for (int u = 0; u < 4; u++) {
        int tl = tq + 8 * u;
        int t = t0 + tl;
        if (t >= 1000) continue;
        float x0 = xs[3 * tl], x1 = xs[3 * tl + 1], x2 = xs[3 * tl + 2];
        ushort4 lo, hi;
        unsigned short* pu = (unsigned short*)&lo;
        #pragma unroll
        for (int jj = 0; jj < 8; jj++) {
            int ci = ci0 + jj;
            float conv = w0s[3 * ci] * x0 + w0s[3 * ci + 1] * x1 + w0s[3 * ci + 2] * x2;
            float v = gelu_f(conv * aco[ci] + cco[ci]);
            if (jj < 4) pu[jj] = f2bf_u(v);
            else ((unsigned short*)&hi)[jj - 4] = f2bf_u(v);
        }
        bf16* orow = h0gT + ((size_t)z * 1000 + t) * 256 + ci0;
        *(ushort4*)orow = lo;
        *(ushort4*)(orow + 4) = hi;
    }
}

// ===========================================================================
// Hybrid MFMA conv GEMM (R5 structure: single swizzled LDS A tile, direct-B,
// 2 barriers/kc, ~13.3KB LDS -> ~29% occupancy) + fused GN+GELU (FUSE) +
// T14 async-stage split: the global loads for tile kc+1 are ISSUED BEFORE
// the MFMA phase of kc (they stay in the vmcnt FIFO across the barrier;
// B-loads are younger, so the compiler's pre-MFMA wait leaves them in
// flight). The gelu + ds_write happen after the post-MFMA barrier with the
// data already resident in VGPRs — load latency is hidden under MFMA.
// aco/cco read via float4 (NOT per-element scalars — R7 regression fixed).
// ===========================================================================
template<int MW, int NW, bool FUSE>
__global__ __launch_bounds__(256) void convT_k(
    const bf16* __restrict__ g, const bf16* __restrict__ Wp,
    const float* __restrict__ bias, bf16* __restrict__ hout,
    float* __restrict__ ssum, float* __restrict__ ssq,
    int T_g, int T_out, int n0,
    const float* __restrict__ pssum, const float* __restrict__ pssq,
    const float* __restrict__ pgam, const float* __restrict__ pbet,
    float pinvCT)
{
    constexpr int CO = 4 * NW * 16;
    constexpr int MT = MW * 16;
    constexpr int NSLOT = MT * 8;          // 16B slots in the A tile
    constexpr int NU = (NSLOT + 255) / 256;
    __shared__ bf16 aT[MT * 64];           // single swizzled A tile
    __shared__ float biasS[CO];
    __shared__ float red[512];
    __shared__ float acoS[256], ccoS[256];
    const int n  = blockIdx.y;
    const int t0 = blockIdx.x * MT;
    const int tid = threadIdx.x;
    for (int i = tid; i < CO; i += 256) biasS[i] = bias[i];
    if (FUSE) {
        float mu = pssum[n0 + n] * pinvCT;
        float rs = rsqrtf(pssq[n0 + n] * pinvCT - mu * mu + 1e-5f);
        float a = rs * pgam[tid];
        acoS[tid] = a;
        ccoS[tid] = pbet[tid] - mu * a;
    }
    const int w = tid >> 6, lane = tid & 63;
    const int l16 = lane & 15, quad = lane >> 4;
    const int sx = l16 & 7;                // read-side swizzle key (row & 7)
    const bf16* gb = g + (size_t)n * T_g * 256;

    // Per-thread staging slot geometry (kc-independent).
    // s_inv: thread's u-th slot doesn't exist (only when NSLOT%256!=0).
    // s_tin==-1 (left pad) / >=T_g (right pad) are VALID slots staging zeros.
    bool s_inv[NU];
    int s_q[NU], s_tin[NU], s_off[NU];
    #pragma unroll
    for (int u = 0; u < NU; u++) {
        int slot = tid + 256 * u;
        s_inv[u] = (NSLOT % 256 != 0) && (slot >= NSLOT);
        if (s_inv[u]) { s_tin[u] = 0x7fffffff; s_q[u] = 0; s_off[u] = 0; continue; }
        int t = slot >> 3, j = slot & 7;
        int ks = j >> 2, q = j & 3;
        s_q[u] = q;
        s_tin[u] = 2 * (t0 + t) - 1 + ks;
        s_off[u] = (t * 8 + (j ^ (t & 7))) * 8;   // swizzled LDS elem offset
    }

    f4v acc[MW][NW];
    #pragma unroll
    for (int i = 0; i < MW; i++)
        #pragma unroll
        for (int j = 0; j < NW; j++) acc[i][j] = (f4v){0.f, 0.f, 0.f, 0.f};

    // acoS/ccoS must be visible before any gelu below.
    if (FUSE) __syncthreads();

    // gelu+GN on one staged 16B slot (float4 aco/cco reads).
    auto act8 = [&](s8v v, int ci0) -> s8v {
        if (FUSE) {
            float4 a0 = *(const float4*)&acoS[ci0], a1 = *(const float4*)&acoS[ci0 + 4];
            float4 c0 = *(const float4*)&ccoS[ci0], c1 = *(const float4*)&ccoS[ci0 + 4];
            float av[8] = {a0.x, a0.y, a0.z, a0.w, a1.x, a1.y, a1.z, a1.w};
            float cv[8] = {c0.x, c0.y, c0.z, c0.w, c1.x, c1.y, c1.z, c1.w};
            unsigned short* uu = (unsigned short*)&v;
            #pragma unroll
            for (int jj = 0; jj < 8; jj++)
                uu[jj] = f2bf_u(gelu_f(bfu2f(uu[jj]) * av[jj] + cv[jj]));
        }
        return v;
    };

    // ---- prologue: stage kc=0 (OOB rows -> zeros)
    #pragma unroll
    for (int u = 0; u < NU; u++) {
        if (s_inv[u]) continue;
        int tin = s_tin[u];
        s8v v = (s8v){0, 0, 0, 0, 0, 0, 0, 0};
        if ((unsigned)tin < (unsigned)T_g)
            v = act8(*(const s8v*)(gb + (size_t)tin * 256 + s_q[u] * 8), s_q[u] * 8);
        *(s8v*)&aT[s_off[u]] = v;
    }
    __syncthreads();

    #pragma unroll 2
    for (int kc = 0; kc < 8; kc++) {
        const int kn = kc + 1;
        // ---- 1. issue kc+1 staging loads FIRST (hide latency under MFMA)
        s8v vst[NU]; bool vok[NU];
        #pragma unroll
        for (int u = 0; u < NU; u++) {
            vst[u] = (s8v){0, 0, 0, 0, 0, 0, 0, 0};
            vok[u] = false;
            if (kn < 8 && !s_inv[u] && (unsigned)s_tin[u] < (unsigned)T_g) {
                vst[u] = *(const s8v*)(gb + (size_t)s_tin[u] * 256 + kn * 32 + s_q[u] * 8);
                vok[u] = true;
            }
        }
        // ---- 2. B fragments for kc (younger in vmcnt FIFO than vst)
        s8v bfr[2][NW];
        #pragma unroll
        for (int ks = 0; ks < 2; ks++)
            #pragma unroll
            for (int j = 0; j < NW; j++) {
                int co = w * NW * 16 + j * 16 + l16;
                bfr[ks][j] = *(const s8v*)(Wp + (size_t)co * 512 + kc * 64 + ks * 32 + quad * 8);
            }
        // ---- 3. ds_read + MFMA on aT (kc data)
        #pragma unroll
        for (int ks = 0; ks < 2; ks++) {
            const int sl = (ks * 4 + quad) ^ sx;   // swizzled 16B slot
            s8v af[MW];
            #pragma unroll
            for (int i = 0; i < MW; i++)
                af[i] = *(const s8v*)&aT[(i * 16 + l16) * 64 + sl * 8];
            #pragma unroll
            for (int i = 0; i < MW; i++)
                #pragma unroll
                for (int j = 0; j < NW; j++)
                    acc[i][j] = __builtin_amdgcn_mfma_f32_16x16x32_bf16(af[i], bfr[ks][j], acc[i][j], 0, 0, 0);
        }
        if (kn < 8) {
            __syncthreads();                 // end of aT reads for kc
            // ---- 4. gelu + ds_write of kc+1 (data already in VGPRs)
            #pragma unroll
            for (int u = 0; u < NU; u++) {
                if (s_inv[u]) continue;
                s8v v = vok[u] ? act8(vst[u], kn * 32 + s_q[u] * 8) : vst[u];
                *(s8v*)&aT[s_off[u]] = v;
            }
            __syncthreads();                 // aT ready for kc+1
        }
    }

    float lsum = 0.f, lsq = 0.f;
    #pragma unroll
    for (int i = 0; i < MW; i++) {
        #pragma unroll
        for (int r = 0; r < 4; r++) {
            int t = t0 + i * 16 + quad * 4 + r;
            if (t < T_out) {
                bf16* orow = hout + ((size_t)n * T_out + t) * CO;
                #pragma unroll
                for (int j = 0; j < NW; j++) {
                    int co = w * NW * 16 + j * 16 + l16;
                    float v = acc[i][j][r] + biasS[co];
                    orow[co] = __float2bfloat16(v);
                    lsum += v; lsq += v * v;
                }
            }
        }
    }
    red[tid] = lsum; red[256 + tid] = lsq;
    __syncthreads();
    for (int st = 128; st > 0; st >>= 1) {
        if (tid < st) { red[tid] += red[tid + st]; red[256 + tid] += red[256 + tid + st]; }
        __syncthreads();
    }
    if (tid == 0) { atomicAdd(&ssum[n0 + n], red[0]); atomicAdd(&ssq[n0 + n], red[256]); }
}

// ---------------------------------------------------------------------------
// Tail kernel 1: GN5+GELU on h5T[n][t][c] + readout 1x1 + msg round-0 pre.
// ---------------------------------------------------------------------------
__global__ __launch_bounds__(256) void readout_pre_k(
    const bf16* __restrict__ h5T, const float* __restrict__ row,
    const float* __restrict__ rob, const float* __restrict__ g5,
    const float* __restrict__ be5, const float* __restrict__ ssum,
    const float* __restrict__ ssq, float invCT,
    const float* __restrict__ mw, const float* __restrict__ mb,
    float* __restrict__ lat0, float* __restrict__ A0, float* __restrict__ Bv0)
{
    __shared__ float lh[2112];   // [t][c] 33 x 64
    __shared__ float ll[2112];   // lat [t][d]
    __shared__ float lw[8192];
    __shared__ float lb[64];
    const int n = blockIdx.x, tid = threadIdx.x;
    const float mu = ssum[n] * invCT;
    const float rs = rsqrtf(ssq[n] * invCT - mu * mu + 1e-5f);
    for (int idx = tid; idx < 2112; idx += 256) {
        int c = idx & 63;
        float a = rs * g5[c];
        float v = __bfloat162float(h5T[(size_t)n * 2112 + idx]) * a + (be5[c] - mu * a);
        lh[idx] = gelu_f(v);
    }
    for (int idx = tid; idx < 4096; idx += 256) lw[idx] = row[idx];
    if (tid < 64) lb[tid] = rob[tid];
    __syncthreads();
    for (int idx = tid; idx < 2112; idx += 256) {
        int t = idx >> 6, d = idx & 63;
        float a = lb[d];
        #pragma unroll 8
        for (int c = 0; c < 64; c++) a += lh[t * 64 + c] * lw[c * 64 + d];
        ll[idx] = a;
        lat0[(size_t)n * 2112 + idx] = a;
    }
    __syncthreads();
    for (int idx = tid; idx < 8192; idx += 256) lw[idx] = mw[idx];
    if (tid < 64) lb[tid] = mb[tid];
    __syncthreads();
    for (int idx = tid; idx < 2112; idx += 256) {
        int t = idx >> 6, d = idx & 63;
        float a = 0.f, bb = lb[d];
        #pragma unroll 8
        for (int k = 0; k < 64; k++) {
            float xv = ll[t * 64 + k];
            a  += xv * lw[k * 64 + d];
            bb += xv * lw[(64 + k) * 64 + d];
        }
        A0[(size_t)n * 2112 + idx]  = a;
        Bv0[(size_t)n * 2112 + idx] = bb;
    }
}

// ---------------------------------------------------------------------------
// Tail kernel 2: msg round-0 combine + msg round-1 pre.
// ---------------------------------------------------------------------------
__global__ __launch_bounds__(256) void comb_pre_k(
    const float* __restrict__ lat0, const float* __restrict__ A0,
    const float* __restrict__ Bv0, const float* __restrict__ mw,
    const float* __restrict__ mb, float* __restrict__ lat1,
    float* __restrict__ A1, float* __restrict__ Bv1)
{
    __shared__ float ll[2112];
    __shared__ float lw[8192];
    __shared__ float lb[64];
    const int n = blockIdx.x, tid = threadIdx.x;
    const int b9 = (n / 9) * 9, j = n - b9;
    for (int idx = tid; idx < 2112; idx += 256) {
        float base = Bv0[(size_t)n * 2112 + idx];
        float s = 0.f;
        #pragma unroll
        for (int i = 0; i < 9; i++) {
            if (i == j) continue;
            s += fmaxf(A0[(size_t)(b9 + i) * 2112 + idx] + base, 0.f);
        }
        float v = lat0[(size_t)n * 2112 + idx] + s * 0.125f;
        ll[idx] = v;
        lat1[(size_t)n * 2112 + idx] = v;
    }
    for (int idx = tid; idx < 8192; idx += 256) lw[idx] = mw[idx];
    if (tid < 64) lb[tid] = mb[tid];
    __syncthreads();
    for (int idx = tid; idx < 2112; idx += 256) {
        int t = idx >> 6, d = idx & 63;
        float a = 0.f, bb = lb[d];
        #pragma unroll 8
        for (int k = 0; k < 64; k++) {
            float xv = ll[t * 64 + k];
            a  += xv * lw[k * 64 + d];
            bb += xv * lw[(64 + k) * 64 + d];
        }
        A1[(size_t)n * 2112 + idx]  = a;
        Bv1[(size_t)n * 2112 + idx] = bb;
    }
}

// ---------------------------------------------------------------------------
// Tail kernel 3: msg round-1 combine + view-sum + readout MLP + projection.
// ---------------------------------------------------------------------------
__global__ __launch_bounds__(256) void final2_k(
    const float* __restrict__ lat1, const float* __restrict__ A1,
    const float* __restrict__ Bv1,
    const float* __restrict__ w1, const float* __restrict__ b1,
    const float* __restrict__ w2, const float* __restrict__ b2,
    const float* __restrict__ pw, const float* __restrict__ pb,
    float* __restrict__ out)
{
    __shared__ float ly[2112], lz[2112];
    __shared__ float lw1[4096], lw2[4096], lpw[2048];
    __shared__ float lb1[64], lb2[64], lpb[32];
    const int b = blockIdx.x, tid = threadIdx.x;
    for (int idx = tid; idx < 4096; idx += 256) { lw1[idx] = w1[idx]; lw2[idx] = w2[idx]; }
    for (int idx = tid; idx < 2048; idx += 256) lpw[idx] = pw[idx];
    if (tid < 64) { lb1[tid] = b1[tid]; lb2[tid] = b2[tid]; }
    if (tid < 32) lpb[tid] = pb[tid];
    for (int idx = tid; idx < 2112; idx += 256) {
        float Av[9], Bb[9], s = 0.f;
        #pragma unroll
        for (int jj = 0; jj < 9; jj++) {
            size_t off = ((size_t)(b * 9 + jj)) * 2112 + idx;
            Av[jj] = A1[off];
            Bb[jj] = Bv1[off];
            s += lat1[off];
        }
        float m = 0.f;
        #pragma unroll
        for (int jj = 0; jj < 9; jj++) {
            float rowsum = 0.f;
            #pragma unroll
            for (int ii = 0; ii < 9; ii++) rowsum += fmaxf(Av[ii] + Bb[jj], 0.f);
            m += rowsum - fmaxf(Av[jj] + Bb[jj], 0.f);
        }
        ly[idx] = s + m * 0.125f;
    }
    __syncthreads();
    for (int idx = tid; idx < 2112; idx += 256) {
        int t = idx >> 6, d = idx & 63;
        float s = lb1[d];
        #pragma unroll 8
        for (int k = 0; k < 64; k++) s += ly[t * 64 + k] * lw1[k * 64 + d];
        lz[idx] = fmaxf(s, 0.f);
    }
    __syncthreads();
    for (int idx = tid; idx < 2112; idx += 256) {
        int t = idx >> 6, d = idx & 63;
        float s = lb2[d];
        #pragma unroll 8
        for (int k = 0; k < 64; k++) s += lz[t * 64 + k] * lw2[k * 64 + d];
        ly[idx] = s * (1.f / 9.f);
    }
    __syncthreads();
    for (int idx = tid; idx < 1056; idx += 256) {
        int e = idx / 33, t = idx - e * 33;
        float s = lpb[e];
        #pragma unroll 8
        for (int d = 0; d < 64; d++) s += ly[t * 64 + d] * lpw[d * 32 + e];
        out[(size_t)b * 1056 + idx] = s;
    }
}

// ---------------------------------------------------------------------------
extern "C" void kernel_launch(void* const* d_in, const int* in_sizes, int n_in,
                              void* d_out, int out_size, void* d_ws, size_t ws_size,
                              hipStream_t stream)
{
    const float* x = (const float*)d_in[0];
    const float* cw[6]; const float* cb[6]; const float* gg[6]; const float* gb[6];
    for (int l = 0; l < 6; l++) {
        cw[l] = (const float*)d_in[1 + 4 * l];
        cb[l] = (const float*)d_in[2 + 4 * l];
        gg[l] = (const float*)d_in[3 + 4 * l];
        gb[l] = (const float*)d_in[4 + 4 * l];
    }
    const float* ro_w = (const float*)d_in[25];
    const float* ro_b = (const float*)d_in[26];
    const float* mw0  = (const float*)d_in[27];
    const float* mb0  = (const float*)d_in[28];
    const float* mw1  = (const float*)d_in[29];
    const float* mb1  = (const float*)d_in[30];
    const float* rw1  = (const float*)d_in[31];
    const float* rb1  = (const float*)d_in[32];
    const float* rw2  = (const float*)d_in[33];
    const float* rb2  = (const float*)d_in[34];
    const float* pw   = (const float*)d_in[35];
    const float* pb   = (const float*)d_in[36];

    // ---- workspace (ws_size = 268,435,456 B measured; peak ~260.1 MB) ----
    // All activation buffers TRANSPOSED: [n][t][ci]. h1..h4 stay RAW
    // (pre-GN); the consuming conv applies GN+GELU in its staging path.
    char* ws = (char*)d_ws;
    bf16* h1T  = (bf16*)(ws);                 // [576][501][256] 147,750,912 B
    bf16* h0gT = (bf16*)(ws + 147750912);     // [192][1000][256] 98,304,000 B (chunk)
    bf16* h2T  = (bf16*)(ws + 147750912);     // [576][251][256] (h0gT dead)
    bf16* h3T  = (bf16*)(ws + 221773824);     // [576][126][256] -> 258,932,736
    bf16* h4T  = (bf16*)(ws);                 // [576][64][256]  (h1T dead)
    bf16* h5T  = (bf16*)(ws + 147750912);     // [576][33][64]   (h2T dead)
    float* lat0 = (float*)(ws);               // 6 x 4,866,048 B (h4T dead after L5)
    float* A0   = lat0 + 1216512;
    float* Bv0  = A0   + 1216512;
    float* lat1 = Bv0  + 1216512;
    float* A1   = lat1 + 1216512;
    float* Bv1  = A1   + 1216512;
    float* stat  = (float*)(ws + 258932736);
    float* mu0   = stat;
    float* rstd0 = stat + 576;
    float* coef  = stat + 1152;               // 16
    float* ssumA = stat + 1168;               // 5 x 576
    float* ssqA  = ssumA + 5 * 576;
    bf16*  Wp    = (bf16*)(ws + 258965504);   // 557,056 bf16 -> 260,079,616
    #define SSUM(l) (ssumA + ((l) - 1) * 576)
    #define SSQ(l)  (ssqA  + ((l) - 1) * 576)

    zero_k<<<(5760 + 255) / 256, 256, 0, stream>>>(ssumA, 2 * 5 * 576);
    wcvt_k<<<(557056 + 255) / 256, 256, 0, stream>>>(cw[1], cw[2], cw[3], cw[4], cw[5], Wp);
    m0red_k<<<1, 256, 0, stream>>>(cw[0], cb[0], coef);
    c0stats_k<<<576, 256, 0, stream>>>(x, coef, mu0, rstd0);

    // ---- layer 1: h0gT (chunked x3) + GEMM (input already activated) ----
    for (int c = 0; c < 3; c++) {
        int n0 = c * 192;
        h0gT_k<<<dim3(32, 192), 256, 0, stream>>>(x, cw[0], cb[0], gg[0], gb[0], mu0, rstd0, h0gT, n0);
        convT_k<4, 4, false><<<dim3(8, 192), 256, 0, stream>>>(
            h0gT, Wp, cb[1], h1T + (size_t)n0 * 501 * 256, SSUM(1), SSQ(1), 1000, 501, n0,
            nullptr, nullptr, nullptr, nullptr, 0.f);
    }

    // ---- layer 2: fused GN1+GELU on raw h1T during staging ----
    convT_k<4, 4, true><<<dim3(4, 576), 256, 0, stream>>>(
        h1T, Wp + 131072, cb[2], h2T, SSUM(2), SSQ(2), 501, 251, 0,
        SSUM(1), SSQ(1), gg[1], gb[1], 1.f / (256.f * 501.f));

    // ---- layer 3: fused GN2+GELU ----
    convT_k<4, 4, true><<<dim3(2, 576), 256, 0, stream>>>(
        h2T, Wp + 262144, cb[3], h3T, SSUM(3), SSQ(3), 251, 126, 0,
        SSUM(2), SSQ(2), gg[2], gb[2], 1.f / (256.f * 251.f));

    // ---- layer 4: fused GN3+GELU ----
    convT_k<4, 4, true><<<dim3(1, 576), 256, 0, stream>>>(
        h3T, Wp + 393216, cb[4], h4T, SSUM(4), SSQ(4), 126, 64, 0,
        SSUM(3), SSQ(3), gg[3], gb[3], 1.f / (256.f * 126.f));

    // ---- layer 5 (CO=64): fused GN4+GELU ----
    convT_k<3, 1, true><<<dim3(1, 576), 256, 0, stream>>>(
        h4T, Wp + 524288, cb[5], h5T, SSUM(5), SSQ(5), 64, 33, 0,
        SSUM(4), SSQ(4), gg[4], gb[4], 1.f / (256.f * 64.f));

    // ---- fused tail: readout+pre0 -> comb0+pre1 -> comb1+sum+MLP+proj ----
    readout_pre_k<<<576, 256, 0, stream>>>(h5T, ro_w, ro_b, gg[5], gb[5],
                                           SSUM(5), SSQ(5), 1.f / (64.f * 33.f),
                                           mw0, mb0, lat0, A0, Bv0);
    comb_pre_k<<<576, 256, 0, stream>>>(lat0, A0, Bv0, mw1, mb1, lat1, A1, Bv1);
    final2_k<<<64, 256, 0, stream>>>(lat1, A1, Bv1, rw1, rb1, rw2, rb2, pw, pb, (float*)d_out);
}

// Round 9
// 768.981 us; speedup vs baseline: 1.1697x; 1.1148x over previous
//
#include <hip/hip_runtime.h>
#include <hip/hip_bf16.h>

typedef __hip_bfloat16 bf16;
typedef __attribute__((ext_vector_type(8))) short s8v;   // 8 bf16 (16B)
typedef __attribute__((ext_vector_type(4))) float f4v;   // 4 f32 (C/D frag)

// Branch-free erf (A&S 7.1.26), |err| < 1.5e-7 — exact at bf16 resolution.
// Uses HW v_rcp_f32 (1 trans op) instead of the IEEE divide expansion.
__device__ __forceinline__ float erf_approx(float x) {
    float ax = fabsf(x);
    float t = __builtin_amdgcn_rcpf(__builtin_fmaf(0.3275911f, ax, 1.0f));
    float p = t * (0.254829592f + t * (-0.284496736f + t * (1.421413741f
              + t * (-1.453152027f + t * 1.061405429f))));
    float r = 1.0f - p * __expf(-ax * ax);
    return copysignf(r, x);
}
__device__ __forceinline__ float gelu_f(float v) {
    return 0.5f * v * (1.f + erf_approx(v * 0.70710678118654752440f));
}
__device__ __forceinline__ unsigned short f2bf_u(float f) {
    bf16 b = __float2bfloat16(f);
    return *(unsigned short*)&b;
}
__device__ __forceinline__ float bfu2f(unsigned short u) {
    bf16 b = *(bf16*)&u;
    return __bfloat162float(b);
}

// ---------------------------------------------------------------------------
__global__ __launch_bounds__(256) void zero_k(float* __restrict__ p, int n) {
    int i = blockIdx.x * 256 + threadIdx.x;
    if (i < n) p[i] = 0.f;
}

// ---------------------------------------------------------------------------
// Convert + K-PERMUTE conv weights W1..W5 fp32 -> bf16.
// Wp[co][kc*64 + s*32 + ci_l] = W[co][kc*32+ci_l][s]  (kc<8, s<2, ci_l<32)
// ---------------------------------------------------------------------------
__global__ __launch_bounds__(256) void wcvt_k(
    const float* __restrict__ w1, const float* __restrict__ w2,
    const float* __restrict__ w3, const float* __restrict__ w4,
    const float* __restrict__ w5, bf16* __restrict__ dst)
{
    int i = blockIdx.x * 256 + threadIdx.x;
    if (i >= 557056) return;
    const float* src; int li;
    if      (i < 131072) { src = w1; li = i; }
    else if (i < 262144) { src = w2; li = i - 131072; }
    else if (i < 393216) { src = w3; li = i - 262144; }
    else if (i < 524288) { src = w4; li = i - 393216; }
    else                 { src = w5; li = i - 524288; }
    int co = li >> 9, rem = li & 511;
    int kc = rem >> 6, rr = rem & 63;
    int s = rr >> 5, cil = rr & 31;
    dst[i] = __float2bfloat16(src[co * 512 + (kc * 32 + cil) * 2 + s]);
}

// ---------------------------------------------------------------------------
// conv0 channel-collapse coefficients (sum over co of v and v^2 as a
// quadratic form in (x0,x1,x2,1)).
// ---------------------------------------------------------------------------
__global__ __launch_bounds__(256) void m0red_k(
    const float* __restrict__ W0, const float* __restrict__ b0, float* __restrict__ coef)
{
    __shared__ float red[256];
    const int co = threadIdx.x;
    float w0 = W0[3 * co], w1 = W0[3 * co + 1], w2 = W0[3 * co + 2], b = b0[co];
    float vals[14] = {w0, w1, w2, b,
                      w0 * w0, w1 * w1, w2 * w2, b * b,
                      2.f * w0 * w1, 2.f * w0 * w2, 2.f * w1 * w2,
                      2.f * w0 * b, 2.f * w1 * b, 2.f * w2 * b};
    for (int k = 0; k < 14; k++) {
        red[co] = vals[k];
        __syncthreads();
        for (int st = 128; st > 0; st >>= 1) {
            if (co < st) red[co] += red[co + st];
            __syncthreads();
        }
        if (co == 0) coef[k] = red[0];
        __syncthreads();
    }
}

// ---------------------------------------------------------------------------
// GN0 stats per node via the collapsed quadratic form. One block per node.
// ---------------------------------------------------------------------------
__global__ __launch_bounds__(256) void c0stats_k(
    const float* __restrict__ x, const float* __restrict__ coef,
    float* __restrict__ mu0, float* __restrict__ rstd0)
{
    __shared__ float xsl[3008];
    __shared__ float red[512];
    const int n = blockIdx.x, tid = threadIdx.x;
    const float* xr = x + (size_t)n * 3000;
    for (int i = tid; i < 750; i += 256) *(float4*)&xsl[4 + 4 * i] = *(const float4*)(xr + 4 * i);
    if (tid < 4) xsl[tid] = 0.f;
    float c[14];
    #pragma unroll
    for (int k = 0; k < 14; k++) c[k] = coef[k];
    __syncthreads();
    float S = 0.f, Q = 0.f;
    if (tid < 250) {
        float f[16];
        #pragma unroll
        for (int k = 0; k < 4; k++) *(float4*)&f[4 * k] = *(const float4*)&xsl[12 * tid + 4 * k];
        #pragma unroll
        for (int j = 0; j < 4; j++) {
            float x0 = f[3 * j + 3], x1 = f[3 * j + 4], x2 = f[3 * j + 5];
            S += c[0] * x0 + c[1] * x1 + c[2] * x2 + c[3];
            Q += c[4] * x0 * x0 + c[5] * x1 * x1 + c[6] * x2 * x2 + c[7]
               + c[8] * x0 * x1 + c[9] * x0 * x2 + c[10] * x1 * x2
               + c[11] * x0 + c[12] * x1 + c[13] * x2;
        }
    }
    red[tid] = S; red[256 + tid] = Q;
    __syncthreads();
    for (int st = 128; st > 0; st >>= 1) {
        if (tid < st) { red[tid] += red[tid + st]; red[256 + tid] += red[256 + tid + st]; }
        __syncthreads();
    }
    if (tid == 0) {
        float m = red[0] * (1.f / 256000.f);
        float var = red[256] * (1.f / 256000.f) - m * m;
        mu0[n] = m;
        rstd0[n] = rsqrtf(var + 1e-5f);
    }
}

// ---------------------------------------------------------------------------
// h0gT[z][t][ci] = gelu(gn0(conv0(x))) bf16, TRANSPOSED layout, node-chunked.
// ---------------------------------------------------------------------------
__global__ __launch_bounds__(256) void h0gT_k(
    const float* __restrict__ x, const float* __restrict__ W0,
    const float* __restrict__ b0, const float* __restrict__ g0,
    const float* __restrict__ be0, const float* __restrict__ mu0,
    const float* __restrict__ rstd0, bf16* __restrict__ h0gT, int n0)
{
    __shared__ float xs[96];
    __shared__ float w0s[768];
    __shared__ float aco[256], cco[256];
    const int z = blockIdx.y;
    const int n = n0 + z;
    const int t0 = blockIdx.x * 32;
    const int tid = threadIdx.x;
    for (int i = tid; i < 768; i += 256) w0s[i] = W0[i];
    {
        float mu = mu0[n], rs = rstd0[n];
        float a = rs * g0[tid];
        aco[tid] = a;
        cco[tid] = (b0[tid] - mu) * a + be0[tid];
    }
    if (tid < 96) {
        int xg = 3 * t0 - 1 + tid;
        xs[tid] = (xg >= 0 && xg < 3000) ? x[(size_t)n * 3000 + xg] : 0.f;
    }
    __syncthreads();
    const int oct = tid & 31, ci0 = oct * 8;
    const int tq = tid >> 5;
    #pragma unroll
    for (int u = 0; u < 4; u++) {
        int tl = tq + 8 * u;
        int t = t0 + tl;
        if (t >= 1000) continue;
        float x0 = xs[3 * tl], x1 = xs[3 * tl + 1], x2 = xs[3 * tl + 2];
        ushort4 lo, hi;
        unsigned short* pu = (unsigned short*)&lo;
        #pragma unroll
        for (int jj = 0; jj < 8; jj++) {
            int ci = ci0 + jj;
            float conv = w0s[3 * ci] * x0 + w0s[3 * ci + 1] * x1 + w0s[3 * ci + 2] * x2;
            float v = gelu_f(conv * aco[ci] + cco[ci]);
            if (jj < 4) pu[jj] = f2bf_u(v);
            else ((unsigned short*)&hi)[jj - 4] = f2bf_u(v);
        }
        bf16* orow = h0gT + ((size_t)z * 1000 + t) * 256 + ci0;
        *(ushort4*)orow = lo;
        *(ushort4*)(orow + 4) = hi;
    }
}

// ===========================================================================
// Hybrid MFMA conv GEMM — R5 structure exactly (single swizzled LDS A tile,
// serial stage[load->gelu->ds_write] -> B-loads -> barrier -> MFMA ->
// barrier; ~80 VGPR, ~29% occupancy) + the R8-PROVEN VALU cuts in the
// serial gelu phase (rcpf-erf, float4 aco/cco) — the gelu phase is serial
// between barriers, so its VALU reduction converts ~1:1 into duration.
// No values held across the MFMA phase (R8's T14 cost 20 VGPR + occupancy
// and hid nothing: the pre-MFMA B-wait drains older staging loads anyway).
// ===========================================================================
template<int MW, int NW, bool FUSE>
__global__ __launch_bounds__(256) void convT_k(
    const bf16* __restrict__ g, const bf16* __restrict__ Wp,
    const float* __restrict__ bias, bf16* __restrict__ hout,
    float* __restrict__ ssum, float* __restrict__ ssq,
    int T_g, int T_out, int n0,
    const float* __restrict__ pssum, const float* __restrict__ pssq,
    const float* __restrict__ pgam, const float* __restrict__ pbet,
    float pinvCT)
{
    constexpr int CO = 4 * NW * 16;
    constexpr int MT = MW * 16;
    constexpr int NSLOT = MT * 8;          // 16B slots in the A tile
    constexpr int NU = (NSLOT + 255) / 256;
    __shared__ bf16 aT[MT * 64];           // single swizzled A tile
    __shared__ float biasS[CO];
    __shared__ float red[512];
    __shared__ float acoS[256], ccoS[256];
    const int n  = blockIdx.y;
    const int t0 = blockIdx.x * MT;
    const int tid = threadIdx.x;
    for (int i = tid; i < CO; i += 256) biasS[i] = bias[i];
    if (FUSE) {
        float mu = pssum[n0 + n] * pinvCT;
        float rs = rsqrtf(pssq[n0 + n] * pinvCT - mu * mu + 1e-5f);
        float a = rs * pgam[tid];
        acoS[tid] = a;
        ccoS[tid] = pbet[tid] - mu * a;
        __syncthreads();               // acoS/ccoS visible to staging below
    }
    const int w = tid >> 6, lane = tid & 63;
    const int l16 = lane & 15, quad = lane >> 4;
    const int sx = l16 & 7;                // read-side swizzle key (row & 7)
    const bf16* gb = g + (size_t)n * T_g * 256;

    // Per-thread staging slot geometry (kc-independent).
    // s_inv: thread's u-th slot doesn't exist (only when NSLOT%256!=0).
    // s_tin==-1 (left pad) / >=T_g (right pad) are VALID slots staging zeros.
    bool s_inv[NU];
    int s_q[NU], s_tin[NU], s_off[NU];
    #pragma unroll
    for (int u = 0; u < NU; u++) {
        int slot = tid + 256 * u;
        s_inv[u] = (NSLOT % 256 != 0) && (slot >= NSLOT);
        if (s_inv[u]) { s_tin[u] = 0x7fffffff; s_q[u] = 0; s_off[u] = 0; continue; }
        int t = slot >> 3, j = slot & 7;
        int ks = j >> 2, q = j & 3;
        s_q[u] = q;
        s_tin[u] = 2 * (t0 + t) - 1 + ks;
        s_off[u] = (t * 8 + (j ^ (t & 7))) * 8;   // swizzled LDS elem offset
    }

    f4v acc[MW][NW];
    #pragma unroll
    for (int i = 0; i < MW; i++)
        #pragma unroll
        for (int j = 0; j < NW; j++) acc[i][j] = (f4v){0.f, 0.f, 0.f, 0.f};

    // gelu+GN on one staged 16B slot (float4 aco/cco reads).
    auto act8 = [&](s8v v, int ci0) -> s8v {
        if (FUSE) {
            float4 a0 = *(const float4*)&acoS[ci0], a1 = *(const float4*)&acoS[ci0 + 4];
            float4 c0 = *(const float4*)&ccoS[ci0], c1 = *(const float4*)&ccoS[ci0 + 4];
            float av[8] = {a0.x, a0.y, a0.z, a0.w, a1.x, a1.y, a1.z, a1.w};
            float cv[8] = {c0.x, c0.y, c0.z, c0.w, c1.x, c1.y, c1.z, c1.w};
            unsigned short* uu = (unsigned short*)&v;
            #pragma unroll
            for (int jj = 0; jj < 8; jj++)
                uu[jj] = f2bf_u(gelu_f(bfu2f(uu[jj]) * av[jj] + cv[jj]));
        }
        return v;
    };

    for (int kc = 0; kc < 8; kc++) {
        // ---- stage A tile: load -> gelu -> swizzled ds_write (serial phase)
        #pragma unroll
        for (int u = 0; u < NU; u++) {
            if (s_inv[u]) continue;
            int tin = s_tin[u];
            s8v v = (s8v){0, 0, 0, 0, 0, 0, 0, 0};
            if ((unsigned)tin < (unsigned)T_g)
                v = act8(*(const s8v*)(gb + (size_t)tin * 256 + kc * 32 + s_q[u] * 8),
                         kc * 32 + s_q[u] * 8);
            *(s8v*)&aT[s_off[u]] = v;
        }
        // ---- B fragments direct from global (independent of LDS)
        s8v bfr[2][NW];
        #pragma unroll
        for (int ks = 0; ks < 2; ks++)
            #pragma unroll
            for (int j = 0; j < NW; j++) {
                int co = w * NW * 16 + j * 16 + l16;
                bfr[ks][j] = *(const s8v*)(Wp + (size_t)co * 512 + kc * 64 + ks * 32 + quad * 8);
            }
        __syncthreads();
        // ---- ds_read + MFMA
        #pragma unroll
        for (int ks = 0; ks < 2; ks++) {
            const int sl = (ks * 4 + quad) ^ sx;   // swizzled 16B slot
            s8v af[MW];
            #pragma unroll
            for (int i = 0; i < MW; i++)
                af[i] = *(const s8v*)&aT[(i * 16 + l16) * 64 + sl * 8];
            #pragma unroll
            for (int i = 0; i < MW; i++)
                #pragma unroll
                for (int j = 0; j < NW; j++)
                    acc[i][j] = __builtin_amdgcn_mfma_f32_16x16x32_bf16(af[i], bfr[ks][j], acc[i][j], 0, 0, 0);
        }
        __syncthreads();
    }

    float lsum = 0.f, lsq = 0.f;
    #pragma unroll
    for (int i = 0; i < MW; i++) {
        #pragma unroll
        for (int r = 0; r < 4; r++) {
            int t = t0 + i * 16 + quad * 4 + r;
            if (t < T_out) {
                bf16* orow = hout + ((size_t)n * T_out + t) * CO;
                #pragma unroll
                for (int j = 0; j < NW; j++) {
                    int co = w * NW * 16 + j * 16 + l16;
                    float v = acc[i][j][r] + biasS[co];
                    orow[co] = __float2bfloat16(v);
                    lsum += v; lsq += v * v;
                }
            }
        }
    }
    red[tid] = lsum; red[256 + tid] = lsq;
    __syncthreads();
    for (int st = 128; st > 0; st >>= 1) {
        if (tid < st) { red[tid] += red[tid + st]; red[256 + tid] += red[256 + tid + st]; }
        __syncthreads();
    }
    if (tid == 0) { atomicAdd(&ssum[n0 + n], red[0]); atomicAdd(&ssq[n0 + n], red[256]); }
}

// ---------------------------------------------------------------------------
// Tail kernel 1: GN5+GELU on h5T[n][t][c] + readout 1x1 + msg round-0 pre.
// ---------------------------------------------------------------------------
__global__ __launch_bounds__(256) void readout_pre_k(
    const bf16* __restrict__ h5T, const float* __restrict__ row,
    const float* __restrict__ rob, const float* __restrict__ g5,
    const float* __restrict__ be5, const float* __restrict__ ssum,
    const float* __restrict__ ssq, float invCT,
    const float* __restrict__ mw, const float* __restrict__ mb,
    float* __restrict__ lat0, float* __restrict__ A0, float* __restrict__ Bv0)
{
    __shared__ float lh[2112];   // [t][c] 33 x 64
    __shared__ float ll[2112];   // lat [t][d]
    __shared__ float lw[8192];
    __shared__ float lb[64];
    const int n = blockIdx.x, tid = threadIdx.x;
    const float mu = ssum[n] * invCT;
    const float rs = rsqrtf(ssq[n] * invCT - mu * mu + 1e-5f);
    for (int idx = tid; idx < 2112; idx += 256) {
        int c = idx & 63;
        float a = rs * g5[c];
        float v = __bfloat162float(h5T[(size_t)n * 2112 + idx]) * a + (be5[c] - mu * a);
        lh[idx] = gelu_f(v);
    }
    for (int idx = tid; idx < 4096; idx += 256) lw[idx] = row[idx];
    if (tid < 64) lb[tid] = rob[tid];
    __syncthreads();
    for (int idx = tid; idx < 2112; idx += 256) {
        int t = idx >> 6, d = idx & 63;
        float a = lb[d];
        #pragma unroll 8
        for (int c = 0; c < 64; c++) a += lh[t * 64 + c] * lw[c * 64 + d];
        ll[idx] = a;
        lat0[(size_t)n * 2112 + idx] = a;
    }
    __syncthreads();
    for (int idx = tid; idx < 8192; idx += 256) lw[idx] = mw[idx];
    if (tid < 64) lb[tid] = mb[tid];
    __syncthreads();
    for (int idx = tid; idx < 2112; idx += 256) {
        int t = idx >> 6, d = idx & 63;
        float a = 0.f, bb = lb[d];
        #pragma unroll 8
        for (int k = 0; k < 64; k++) {
            float xv = ll[t * 64 + k];
            a  += xv * lw[k * 64 + d];
            bb += xv * lw[(64 + k) * 64 + d];
        }
        A0[(size_t)n * 2112 + idx]  = a;
        Bv0[(size_t)n * 2112 + idx] = bb;
    }
}

// ---------------------------------------------------------------------------
// Tail kernel 2: msg round-0 combine + msg round-1 pre.
// ---------------------------------------------------------------------------
__global__ __launch_bounds__(256) void comb_pre_k(
    const float* __restrict__ lat0, const float* __restrict__ A0,
    const float* __restrict__ Bv0, const float* __restrict__ mw,
    const float* __restrict__ mb, float* __restrict__ lat1,
    float* __restrict__ A1, float* __restrict__ Bv1)
{
    __shared__ float ll[2112];
    __shared__ float lw[8192];
    __shared__ float lb[64];
    const int n = blockIdx.x, tid = threadIdx.x;
    const int b9 = (n / 9) * 9, j = n - b9;
    for (int idx = tid; idx < 2112; idx += 256) {
        float base = Bv0[(size_t)n * 2112 + idx];
        float s = 0.f;
        #pragma unroll
        for (int i = 0; i < 9; i++) {
            if (i == j) continue;
            s += fmaxf(A0[(size_t)(b9 + i) * 2112 + idx] + base, 0.f);
        }
        float v = lat0[(size_t)n * 2112 + idx] + s * 0.125f;
        ll[idx] = v;
        lat1[(size_t)n * 2112 + idx] = v;
    }
    for (int idx = tid; idx < 8192; idx += 256) lw[idx] = mw[idx];
    if (tid < 64) lb[tid] = mb[tid];
    __syncthreads();
    for (int idx = tid; idx < 2112; idx += 256) {
        int t = idx >> 6, d = idx & 63;
        float a = 0.f, bb = lb[d];
        #pragma unroll 8
        for (int k = 0; k < 64; k++) {
            float xv = ll[t * 64 + k];
            a  += xv * lw[k * 64 + d];
            bb += xv * lw[(64 + k) * 64 + d];
        }
        A1[(size_t)n * 2112 + idx]  = a;
        Bv1[(size_t)n * 2112 + idx] = bb;
    }
}

// ---------------------------------------------------------------------------
// Tail kernel 3: msg round-1 combine + view-sum + readout MLP + projection.
// ---------------------------------------------------------------------------
__global__ __launch_bounds__(256) void final2_k(
    const float* __restrict__ lat1, const float* __restrict__ A1,
    const float* __restrict__ Bv1,
    const float* __restrict__ w1, const float* __restrict__ b1,
    const float* __restrict__ w2, const float* __restrict__ b2,
    const float* __restrict__ pw, const float* __restrict__ pb,
    float* __restrict__ out)
{
    __shared__ float ly[2112], lz[2112];
    __shared__ float lw1[4096], lw2[4096], lpw[2048];
    __shared__ float lb1[64], lb2[64], lpb[32];
    const int b = blockIdx.x, tid = threadIdx.x;
    for (int idx = tid; idx < 4096; idx += 256) { lw1[idx] = w1[idx]; lw2[idx] = w2[idx]; }
    for (int idx = tid; idx < 2048; idx += 256) lpw[idx] = pw[idx];
    if (tid < 64) { lb1[tid] = b1[tid]; lb2[tid] = b2[tid]; }
    if (tid < 32) lpb[tid] = pb[tid];
    for (int idx = tid; idx < 2112; idx += 256) {
        float Av[9], Bb[9], s = 0.f;
        #pragma unroll
        for (int jj = 0; jj < 9; jj++) {
            size_t off = ((size_t)(b * 9 + jj)) * 2112 + idx;
            Av[jj] = A1[off];
            Bb[jj] = Bv1[off];
            s += lat1[off];
        }
        float m = 0.f;
        #pragma unroll
        for (int jj = 0; jj < 9; jj++) {
            float rowsum = 0.f;
            #pragma unroll
            for (int ii = 0; ii < 9; ii++) rowsum += fmaxf(Av[ii] + Bb[jj], 0.f);
            m += rowsum - fmaxf(Av[jj] + Bb[jj], 0.f);
        }
        ly[idx] = s + m * 0.125f;
    }
    __syncthreads();
    for (int idx = tid; idx < 2112; idx += 256) {
        int t = idx >> 6, d = idx & 63;
        float s = lb1[d];
        #pragma unroll 8
        for (int k = 0; k < 64; k++) s += ly[t * 64 + k] * lw1[k * 64 + d];
        lz[idx] = fmaxf(s, 0.f);
    }
    __syncthreads();
    for (int idx = tid; idx < 2112; idx += 256) {
        int t = idx >> 6, d = idx & 63;
        float s = lb2[d];
        #pragma unroll 8
        for (int k = 0; k < 64; k++) s += lz[t * 64 + k] * lw2[k * 64 + d];
        ly[idx] = s * (1.f / 9.f);
    }
    __syncthreads();
    for (int idx = tid; idx < 1056; idx += 256) {
        int e = idx / 33, t = idx - e * 33;
        float s = lpb[e];
        #pragma unroll 8
        for (int d = 0; d < 64; d++) s += ly[t * 64 + d] * lpw[d * 32 + e];
        out[(size_t)b * 1056 + idx] = s;
    }
}

// ---------------------------------------------------------------------------
extern "C" void kernel_launch(void* const* d_in, const int* in_sizes, int n_in,
                              void* d_out, int out_size, void* d_ws, size_t ws_size,
                              hipStream_t stream)
{
    const float* x = (const float*)d_in[0];
    const float* cw[6]; const float* cb[6]; const float* gg[6]; const float* gb[6];
    for (int l = 0; l < 6; l++) {
        cw[l] = (const float*)d_in[1 + 4 * l];
        cb[l] = (const float*)d_in[2 + 4 * l];
        gg[l] = (const float*)d_in[3 + 4 * l];
        gb[l] = (const float*)d_in[4 + 4 * l];
    }
    const float* ro_w = (const float*)d_in[25];
    const float* ro_b = (const float*)d_in[26];
    const float* mw0  = (const float*)d_in[27];
    const float* mb0  = (const float*)d_in[28];
    const float* mw1  = (const float*)d_in[29];
    const float* mb1  = (const float*)d_in[30];
    const float* rw1  = (const float*)d_in[31];
    const float* rb1  = (const float*)d_in[32];
    const float* rw2  = (const float*)d_in[33];
    const float* rb2  = (const float*)d_in[34];
    const float* pw   = (const float*)d_in[35];
    const float* pb   = (const float*)d_in[36];

    // ---- workspace (ws_size = 268,435,456 B measured; peak ~260.1 MB) ----
    // All activation buffers TRANSPOSED: [n][t][ci]. h1..h4 stay RAW
    // (pre-GN); the consuming conv applies GN+GELU in its staging path.
    char* ws = (char*)d_ws;
    bf16* h1T  = (bf16*)(ws);                 // [576][501][256] 147,750,912 B
    bf16* h0gT = (bf16*)(ws + 147750912);     // [192][1000][256] 98,304,000 B (chunk)
    bf16* h2T  = (bf16*)(ws + 147750912);     // [576][251][256] (h0gT dead)
    bf16* h3T  = (bf16*)(ws + 221773824);     // [576][126][256] -> 258,932,736
    bf16* h4T  = (bf16*)(ws);                 // [576][64][256]  (h1T dead)
    bf16* h5T  = (bf16*)(ws + 147750912);     // [576][33][64]   (h2T dead)
    float* lat0 = (float*)(ws);               // 6 x 4,866,048 B (h4T dead after L5)
    float* A0   = lat0 + 1216512;
    float* Bv0  = A0   + 1216512;
    float* lat1 = Bv0  + 1216512;
    float* A1   = lat1 + 1216512;
    float* Bv1  = A1   + 1216512;
    float* stat  = (float*)(ws + 258932736);
    float* mu0   = stat;
    float* rstd0 = stat + 576;
    float* coef  = stat + 1152;               // 16
    float* ssumA = stat + 1168;               // 5 x 576
    float* ssqA  = ssumA + 5 * 576;
    bf16*  Wp    = (bf16*)(ws + 258965504);   // 557,056 bf16 -> 260,079,616
    #define SSUM(l) (ssumA + ((l) - 1) * 576)
    #define SSQ(l)  (ssqA  + ((l) - 1) * 576)

    zero_k<<<(5760 + 255) / 256, 256, 0, stream>>>(ssumA, 2 * 5 * 576);
    wcvt_k<<<(557056 + 255) / 256, 256, 0, stream>>>(cw[1], cw[2], cw[3], cw[4], cw[5], Wp);
    m0red_k<<<1, 256, 0, stream>>>(cw[0], cb[0], coef);
    c0stats_k<<<576, 256, 0, stream>>>(x, coef, mu0, rstd0);

    // ---- layer 1: h0gT (chunked x3) + GEMM (input already activated) ----
    for (int c = 0; c < 3; c++) {
        int n0 = c * 192;
        h0gT_k<<<dim3(32, 192), 256, 0, stream>>>(x, cw[0], cb[0], gg[0], gb[0], mu0, rstd0, h0gT, n0);
        convT_k<4, 4, false><<<dim3(8, 192), 256, 0, stream>>>(
            h0gT, Wp, cb[1], h1T + (size_t)n0 * 501 * 256, SSUM(1), SSQ(1), 1000, 501, n0,
            nullptr, nullptr, nullptr, nullptr, 0.f);
    }

    // ---- layer 2: fused GN1+GELU on raw h1T during staging ----
    convT_k<4, 4, true><<<dim3(4, 576), 256, 0, stream>>>(
        h1T, Wp + 131072, cb[2], h2T, SSUM(2), SSQ(2), 501, 251, 0,
        SSUM(1), SSQ(1), gg[1], gb[1], 1.f / (256.f * 501.f));

    // ---- layer 3: fused GN2+GELU ----
    convT_k<4, 4, true><<<dim3(2, 576), 256, 0, stream>>>(
        h2T, Wp + 262144, cb[3], h3T, SSUM(3), SSQ(3), 251, 126, 0,
        SSUM(2), SSQ(2), gg[2], gb[2], 1.f / (256.f * 251.f));

    // ---- layer 4: fused GN3+GELU ----
    convT_k<4, 4, true><<<dim3(1, 576), 256, 0, stream>>>(
        h3T, Wp + 393216, cb[4], h4T, SSUM(4), SSQ(4), 126, 64, 0,
        SSUM(3), SSQ(3), gg[3], gb[3], 1.f / (256.f * 126.f));

    // ---- layer 5 (CO=64): fused GN4+GELU ----
    convT_k<3, 1, true><<<dim3(1, 576), 256, 0, stream>>>(
        h4T, Wp + 524288, cb[5], h5T, SSUM(5), SSQ(5), 64, 33, 0,
        SSUM(4), SSQ(4), gg[4], gb[4], 1.f / (256.f * 64.f));

    // ---- fused tail: readout+pre0 -> comb0+pre1 -> comb1+sum+MLP+proj ----
    readout_pre_k<<<576, 256, 0, stream>>>(h5T, ro_w, ro_b, gg[5], gb[5],
                                           SSUM(5), SSQ(5), 1.f / (64.f * 33.f),
                                           mw0, mb0, lat0, A0, Bv0);
    comb_pre_k<<<576, 256, 0, stream>>>(lat0, A0, Bv0, mw1, mb1, lat1, A1, Bv1);
    final2_k<<<64, 256, 0, stream>>>(lat1, A1, Bv1, rw1, rb1, rw2, rb2, pw, pb, (float*)d_out);
}

// Round 10
// 673.890 us; speedup vs baseline: 1.3347x; 1.1411x over previous
//
#include <hip/hip_runtime.h>
#include <hip/hip_bf16.h>

typedef __hip_bfloat16 bf16;
typedef __attribute__((ext_vector_type(8))) short s8v;   // 8 bf16 (16B)
typedef __attribute__((ext_vector_type(4))) float f4v;   // 4 f32 (C/D frag)

// Branch-free erf (A&S 7.1.26), |err| < 1.5e-7 — exact at bf16 resolution.
// Uses HW v_rcp_f32 (1 trans op) instead of the IEEE divide expansion.
__device__ __forceinline__ float erf_approx(float x) {
    float ax = fabsf(x);
    float t = __builtin_amdgcn_rcpf(__builtin_fmaf(0.3275911f, ax, 1.0f));
    float p = t * (0.254829592f + t * (-0.284496736f + t * (1.421413741f
              + t * (-1.453152027f + t * 1.061405429f))));
    float r = 1.0f - p * __expf(-ax * ax);
    return copysignf(r, x);
}
__device__ __forceinline__ float gelu_f(float v) {
    return 0.5f * v * (1.f + erf_approx(v * 0.70710678118654752440f));
}
__device__ __forceinline__ unsigned short f2bf_u(float f) {
    bf16 b = __float2bfloat16(f);
    return *(unsigned short*)&b;
}
__device__ __forceinline__ float bfu2f(unsigned short u) {
    bf16 b = *(bf16*)&u;
    return __bfloat162float(b);
}

// ---------------------------------------------------------------------------
__global__ __launch_bounds__(256) void zero_k(float* __restrict__ p, int n) {
    int i = blockIdx.x * 256 + threadIdx.x;
    if (i < n) p[i] = 0.f;
}

// ---------------------------------------------------------------------------
// Convert + K-PERMUTE conv weights W1..W5 fp32 -> bf16.
// Wp[co][kc*64 + s*32 + ci_l] = W[co][kc*32+ci_l][s]  (kc<8, s<2, ci_l<32)
// ---------------------------------------------------------------------------
__global__ __launch_bounds__(256) void wcvt_k(
    const float* __restrict__ w1, const float* __restrict__ w2,
    const float* __restrict__ w3, const float* __restrict__ w4,
    const float* __restrict__ w5, bf16* __restrict__ dst)
{
    int i = blockIdx.x * 256 + threadIdx.x;
    if (i >= 557056) return;
    const float* src; int li;
    if      (i < 131072) { src = w1; li = i; }
    else if (i < 262144) { src = w2; li = i - 131072; }
    else if (i < 393216) { src = w3; li = i - 262144; }
    else if (i < 524288) { src = w4; li = i - 393216; }
    else                 { src = w5; li = i - 524288; }
    int co = li >> 9, rem = li & 511;
    int kc = rem >> 6, rr = rem & 63;
    int s = rr >> 5, cil = rr & 31;
    dst[i] = __float2bfloat16(src[co * 512 + (kc * 32 + cil) * 2 + s]);
}

// ---------------------------------------------------------------------------
// conv0 channel-collapse coefficients + conv0 TAP-PLANES w0t (f32):
// w0t[co] = W0[co][0], w0t[256+co] = W0[co][1], w0t[512+co] = W0[co][2].
// ---------------------------------------------------------------------------
__global__ __launch_bounds__(256) void m0red_k(
    const float* __restrict__ W0, const float* __restrict__ b0,
    float* __restrict__ coef, float* __restrict__ w0t)
{
    __shared__ float red[256];
    const int co = threadIdx.x;
    float w0 = W0[3 * co], w1 = W0[3 * co + 1], w2 = W0[3 * co + 2], b = b0[co];
    w0t[co] = w0; w0t[256 + co] = w1; w0t[512 + co] = w2;
    float vals[14] = {w0, w1, w2, b,
                      w0 * w0, w1 * w1, w2 * w2, b * b,
                      2.f * w0 * w1, 2.f * w0 * w2, 2.f * w1 * w2,
                      2.f * w0 * b, 2.f * w1 * b, 2.f * w2 * b};
    for (int k = 0; k < 14; k++) {
        red[co] = vals[k];
        __syncthreads();
        for (int st = 128; st > 0; st >>= 1) {
            if (co < st) red[co] += red[co + st];
            __syncthreads();
        }
        if (co == 0) coef[k] = red[0];
        __syncthreads();
    }
}

// ---------------------------------------------------------------------------
// GN0 stats per node via the collapsed quadratic form. One block per node.
// ---------------------------------------------------------------------------
__global__ __launch_bounds__(256) void c0stats_k(
    const float* __restrict__ x, const float* __restrict__ coef,
    float* __restrict__ mu0, float* __restrict__ rstd0)
{
    __shared__ float xsl[3008];
    __shared__ float red[512];
    const int n = blockIdx.x, tid = threadIdx.x;
    const float* xr = x + (size_t)n * 3000;
    for (int i = tid; i < 750; i += 256) *(float4*)&xsl[4 + 4 * i] = *(const float4*)(xr + 4 * i);
    if (tid < 4) xsl[tid] = 0.f;
    float c[14];
    #pragma unroll
    for (int k = 0; k < 14; k++) c[k] = coef[k];
    __syncthreads();
    float S = 0.f, Q = 0.f;
    if (tid < 250) {
        float f[16];
        #pragma unroll
        for (int k = 0; k < 4; k++) *(float4*)&f[4 * k] = *(const float4*)&xsl[12 * tid + 4 * k];
        #pragma unroll
        for (int j = 0; j < 4; j++) {
            float x0 = f[3 * j + 3], x1 = f[3 * j + 4], x2 = f[3 * j + 5];
            S += c[0] * x0 + c[1] * x1 + c[2] * x2 + c[3];
            Q += c[4] * x0 * x0 + c[5] * x1 * x1 + c[6] * x2 * x2 + c[7]
               + c[8] * x0 * x1 + c[9] * x0 * x2 + c[10] * x1 * x2
               + c[11] * x0 + c[12] * x1 + c[13] * x2;
        }
    }
    red[tid] = S; red[256 + tid] = Q;
    __syncthreads();
    for (int st = 128; st > 0; st >>= 1) {
        if (tid < st) { red[tid] += red[tid + st]; red[256 + tid] += red[256 + tid + st]; }
        __syncthreads();
    }
    if (tid == 0) {
        float m = red[0] * (1.f / 256000.f);
        float var = red[256] * (1.f / 256000.f) - m * m;
        mu0[n] = m;
        rstd0[n] = rsqrtf(var + 1e-5f);
    }
}

// ===========================================================================
// Hybrid MFMA conv GEMM — R9 structure (single swizzled LDS A tile, serial
// stage -> B-loads -> barrier -> MFMA -> barrier; rcpf-erf; float4 coefs).
// MODE 1: A input is RAW prev-conv output; staging applies GN+GELU.
// MODE 2 (layer 1): A is COMPUTED IN-PLACE from x: conv0 (width-3, 1->256ch)
//   + GN0 + GELU0, using LDS-staged x window (387 f32) and w0 tap planes.
//   No h0gT materialization, no global loads in the staging phase at all.
//   Numerically identical to the old h0gT_k path (same f32 conv, same gelu,
//   same f2bf rounding point).
// ===========================================================================
template<int MW, int NW, int MODE>
__global__ __launch_bounds__(256) void convT_k(
    const bf16* __restrict__ g, const float* __restrict__ xraw,
    const float* __restrict__ w0t, const bf16* __restrict__ Wp,
    const float* __restrict__ bias, const float* __restrict__ b0c,
    bf16* __restrict__ hout, float* __restrict__ ssum, float* __restrict__ ssq,
    int T_g, int T_out, int n0,
    const float* __restrict__ pssum, const float* __restrict__ pssq,
    const float* __restrict__ pgam, const float* __restrict__ pbet,
    float pinvCT)
{
    constexpr int CO = 4 * NW * 16;
    constexpr int MT = MW * 16;
    constexpr int NSLOT = MT * 8;          // 16B slots in the A tile
    constexpr int NU = (NSLOT + 255) / 256;
    __shared__ bf16 aT[MT * 64];           // single swizzled A tile
    __shared__ float biasS[CO];
    __shared__ float red[512];
    __shared__ float acoS[256], ccoS[256];
    __shared__ float xs[(MODE == 2) ? 400 : 1];    // x window (MODE 2)
    __shared__ float w0s[(MODE == 2) ? 768 : 1];   // conv0 tap planes (MODE 2)
    const int n  = blockIdx.y;
    const int t0 = blockIdx.x * MT;
    const int tid = threadIdx.x;
    for (int i = tid; i < CO; i += 256) biasS[i] = bias[i];
    if (MODE == 1) {
        float mu = pssum[n0 + n] * pinvCT;
        float rs = rsqrtf(pssq[n0 + n] * pinvCT - mu * mu + 1e-5f);
        float a = rs * pgam[tid];
        acoS[tid] = a;
        ccoS[tid] = pbet[tid] - mu * a;
        __syncthreads();               // coefs visible to staging below
    } else { // MODE 2
        float mu = pssum[n];           // mu0[n]
        float rs = pssq[n];            // rstd0[n]
        float a = rs * pgam[tid];
        acoS[tid] = a;
        ccoS[tid] = (b0c[tid] - mu) * a + pbet[tid];
        for (int i = tid; i < 768; i += 256) w0s[i] = w0t[i];
        const float* xr = xraw + (size_t)n * 3000;
        for (int i = tid; i < 400; i += 256) {
            int xg = 6 * t0 - 4 + i;
            xs[i] = ((unsigned)xg < 3000u) ? xr[xg] : 0.f;
        }
        __syncthreads();
    }
    const int w = tid >> 6, lane = tid & 63;
    const int l16 = lane & 15, quad = lane >> 4;
    const int sx = l16 & 7;                // read-side swizzle key (row & 7)
    const bf16* gb = (MODE == 2) ? nullptr : (g + (size_t)n * T_g * 256);

    // Per-thread staging slot geometry (kc-independent).
    // s_inv: thread's u-th slot doesn't exist (only when NSLOT%256!=0).
    // s_tin==-1 (left pad) / >=T_g (right pad) are VALID slots staging zeros.
    bool s_inv[NU];
    int s_q[NU], s_tin[NU], s_off[NU];
    #pragma unroll
    for (int u = 0; u < NU; u++) {
        int slot = tid + 256 * u;
        s_inv[u] = (NSLOT % 256 != 0) && (slot >= NSLOT);
        if (s_inv[u]) { s_tin[u] = 0x7fffffff; s_q[u] = 0; s_off[u] = 0; continue; }
        int t = slot >> 3, j = slot & 7;
        int ks = j >> 2, q = j & 3;
        s_q[u] = q;
        s_tin[u] = 2 * (t0 + t) - 1 + ks;
        s_off[u] = (t * 8 + (j ^ (t & 7))) * 8;   // swizzled LDS elem offset
    }

    f4v acc[MW][NW];
    #pragma unroll
    for (int i = 0; i < MW; i++)
        #pragma unroll
        for (int j = 0; j < NW; j++) acc[i][j] = (f4v){0.f, 0.f, 0.f, 0.f};

    for (int kc = 0; kc < 8; kc++) {
        // ---- stage A tile (serial phase between barriers)
        #pragma unroll
        for (int u = 0; u < NU; u++) {
            if (s_inv[u]) continue;
            int tin = s_tin[u];
            s8v v = (s8v){0, 0, 0, 0, 0, 0, 0, 0};
            if ((unsigned)tin < (unsigned)T_g) {
                const int ci0 = kc * 32 + s_q[u] * 8;
                float4 a0 = *(const float4*)&acoS[ci0], a1 = *(const float4*)&acoS[ci0 + 4];
                float4 c0 = *(const float4*)&ccoS[ci0], c1 = *(const float4*)&ccoS[ci0 + 4];
                float av[8] = {a0.x, a0.y, a0.z, a0.w, a1.x, a1.y, a1.z, a1.w};
                float cv[8] = {c0.x, c0.y, c0.z, c0.w, c1.x, c1.y, c1.z, c1.w};
                unsigned short* uu = (unsigned short*)&v;
                if (MODE == 2) {
                    // conv0 from x window + GN0 + GELU0
                    int lx = 3 * (tin - 2 * t0) + 3;   // index of x[3*tin-1] in xs
                    float x0 = xs[lx], x1 = xs[lx + 1], x2 = xs[lx + 2];
                    float4 wa0 = *(const float4*)&w0s[ci0],       wa1 = *(const float4*)&w0s[ci0 + 4];
                    float4 wb0 = *(const float4*)&w0s[256 + ci0], wb1 = *(const float4*)&w0s[256 + ci0 + 4];
                    float4 wc0 = *(const float4*)&w0s[512 + ci0], wc1 = *(const float4*)&w0s[512 + ci0 + 4];
                    float wav[8] = {wa0.x, wa0.y, wa0.z, wa0.w, wa1.x, wa1.y, wa1.z, wa1.w};
                    float wbv[8] = {wb0.x, wb0.y, wb0.z, wb0.w, wb1.x, wb1.y, wb1.z, wb1.w};
                    float wcv[8] = {wc0.x, wc0.y, wc0.z, wc0.w, wc1.x, wc1.y, wc1.z, wc1.w};
                    #pragma unroll
                    for (int jj = 0; jj < 8; jj++) {
                        float conv = wav[jj] * x0 + wbv[jj] * x1 + wcv[jj] * x2;
                        uu[jj] = f2bf_u(gelu_f(conv * av[jj] + cv[jj]));
                    }
                } else {
                    // load raw prev-conv output + GN + GELU
                    v = *(const s8v*)(gb + (size_t)tin * 256 + ci0 - kc * 32 + kc * 32 + s_q[u] * 8 - s_q[u] * 8);
                    v = *(const s8v*)(gb + (size_t)tin * 256 + kc * 32 + s_q[u] * 8);
                    #pragma unroll
                    for (int jj = 0; jj < 8; jj++)
                        uu[jj] = f2bf_u(gelu_f(bfu2f(uu[jj]) * av[jj] + cv[jj]));
                }
            }
            *(s8v*)&aT[s_off[u]] = v;
        }
        // ---- B fragments direct from global (independent of LDS)
        s8v bfr[2][NW];
        #pragma unroll
        for (int ks = 0; ks < 2; ks++)
            #pragma unroll
            for (int j = 0; j < NW; j++) {
                int co = w * NW * 16 + j * 16 + l16;
                bfr[ks][j] = *(const s8v*)(Wp + (size_t)co * 512 + kc * 64 + ks * 32 + quad * 8);
            }
        __syncthreads();
        // ---- ds_read + MFMA
        #pragma unroll
        for (int ks = 0; ks < 2; ks++) {
            const int sl = (ks * 4 + quad) ^ sx;   // swizzled 16B slot
            s8v af[MW];
            #pragma unroll
            for (int i = 0; i < MW; i++)
                af[i] = *(const s8v*)&aT[(i * 16 + l16) * 64 + sl * 8];
            #pragma unroll
            for (int i = 0; i < MW; i++)
                #pragma unroll
                for (int j = 0; j < NW; j++)
                    acc[i][j] = __builtin_amdgcn_mfma_f32_16x16x32_bf16(af[i], bfr[ks][j], acc[i][j], 0, 0, 0);
        }
        __syncthreads();
    }

    float lsum = 0.f, lsq = 0.f;
    #pragma unroll
    for (int i = 0; i < MW; i++) {
        #pragma unroll
        for (int r = 0; r < 4; r++) {
            int t = t0 + i * 16 + quad * 4 + r;
            if (t < T_out) {
                bf16* orow = hout + ((size_t)n * T_out + t) * CO;
                #pragma unroll
                for (int j = 0; j < NW; j++) {
                    int co = w * NW * 16 + j * 16 + l16;
                    float v = acc[i][j][r] + biasS[co];
                    orow[co] = __float2bfloat16(v);
                    lsum += v; lsq += v * v;
                }
            }
        }
    }
    red[tid] = lsum; red[256 + tid] = lsq;
    __syncthreads();
    for (int st = 128; st > 0; st >>= 1) {
        if (tid < st) { red[tid] += red[tid + st]; red[256 + tid] += red[256 + tid + st]; }
        __syncthreads();
    }
    if (tid == 0) { atomicAdd(&ssum[n0 + n], red[0]); atomicAdd(&ssq[n0 + n], red[256]); }
}

// ---------------------------------------------------------------------------
// Tail kernel 1: GN5+GELU on h5T[n][t][c] + readout 1x1 + msg round-0 pre.
// ---------------------------------------------------------------------------
__global__ __launch_bounds__(256) void readout_pre_k(
    const bf16* __restrict__ h5T, const float* __restrict__ row,
    const float* __restrict__ rob, const float* __restrict__ g5,
    const float* __restrict__ be5, const float* __restrict__ ssum,
    const float* __restrict__ ssq, float invCT,
    const float* __restrict__ mw, const float* __restrict__ mb,
    float* __restrict__ lat0, float* __restrict__ A0, float* __restrict__ Bv0)
{
    __shared__ float lh[2112];   // [t][c] 33 x 64
    __shared__ float ll[2112];   // lat [t][d]
    __shared__ float lw[8192];
    __shared__ float lb[64];
    const int n = blockIdx.x, tid = threadIdx.x;
    const float mu = ssum[n] * invCT;
    const float rs = rsqrtf(ssq[n] * invCT - mu * mu + 1e-5f);
    for (int idx = tid; idx < 2112; idx += 256) {
        int c = idx & 63;
        float a = rs * g5[c];
        float v = __bfloat162float(h5T[(size_t)n * 2112 + idx]) * a + (be5[c] - mu * a);
        lh[idx] = gelu_f(v);
    }
    for (int idx = tid; idx < 4096; idx += 256) lw[idx] = row[idx];
    if (tid < 64) lb[tid] = rob[tid];
    __syncthreads();
    for (int idx = tid; idx < 2112; idx += 256) {
        int t = idx >> 6, d = idx & 63;
        float a = lb[d];
        #pragma unroll 8
        for (int c = 0; c < 64; c++) a += lh[t * 64 + c] * lw[c * 64 + d];
        ll[idx] = a;
        lat0[(size_t)n * 2112 + idx] = a;
    }
    __syncthreads();
    for (int idx = tid; idx < 8192; idx += 256) lw[idx] = mw[idx];
    if (tid < 64) lb[tid] = mb[tid];
    __syncthreads();
    for (int idx = tid; idx < 2112; idx += 256) {
        int t = idx >> 6, d = idx & 63;
        float a = 0.f, bb = lb[d];
        #pragma unroll 8
        for (int k = 0; k < 64; k++) {
            float xv = ll[t * 64 + k];
            a  += xv * lw[k * 64 + d];
            bb += xv * lw[(64 + k) * 64 + d];
        }
        A0[(size_t)n * 2112 + idx]  = a;
        Bv0[(size_t)n * 2112 + idx] = bb;
    }
}

// ---------------------------------------------------------------------------
// Tail kernel 2: msg round-0 combine + msg round-1 pre.
// ---------------------------------------------------------------------------
__global__ __launch_bounds__(256) void comb_pre_k(
    const float* __restrict__ lat0, const float* __restrict__ A0,
    const float* __restrict__ Bv0, const float* __restrict__ mw,
    const float* __restrict__ mb, float* __restrict__ lat1,
    float* __restrict__ A1, float* __restrict__ Bv1)
{
    __shared__ float ll[2112];
    __shared__ float lw[8192];
    __shared__ float lb[64];
    const int n = blockIdx.x, tid = threadIdx.x;
    const int b9 = (n / 9) * 9, j = n - b9;
    for (int idx = tid; idx < 2112; idx += 256) {
        float base = Bv0[(size_t)n * 2112 + idx];
        float s = 0.f;
        #pragma unroll
        for (int i = 0; i < 9; i++) {
            if (i == j) continue;
            s += fmaxf(A0[(size_t)(b9 + i) * 2112 + idx] + base, 0.f);
        }
        float v = lat0[(size_t)n * 2112 + idx] + s * 0.125f;
        ll[idx] = v;
        lat1[(size_t)n * 2112 + idx] = v;
    }
    for (int idx = tid; idx < 8192; idx += 256) lw[idx] = mw[idx];
    if (tid < 64) lb[tid] = mb[tid];
    __syncthreads();
    for (int idx = tid; idx < 2112; idx += 256) {
        int t = idx >> 6, d = idx & 63;
        float a = 0.f, bb = lb[d];
        #pragma unroll 8
        for (int k = 0; k < 64; k++) {
            float xv = ll[t * 64 + k];
            a  += xv * lw[k * 64 + d];
            bb += xv * lw[(64 + k) * 64 + d];
        }
        A1[(size_t)n * 2112 + idx]  = a;
        Bv1[(size_t)n * 2112 + idx] = bb;
    }
}

// ---------------------------------------------------------------------------
// Tail kernel 3: msg round-1 combine + view-sum + readout MLP + projection.
// ---------------------------------------------------------------------------
__global__ __launch_bounds__(256) void final2_k(
    const float* __restrict__ lat1, const float* __restrict__ A1,
    const float* __restrict__ Bv1,
    const float* __restrict__ w1, const float* __restrict__ b1,
    const float* __restrict__ w2, const float* __restrict__ b2,
    const float* __restrict__ pw, const float* __restrict__ pb,
    float* __restrict__ out)
{
    __shared__ float ly[2112], lz[2112];
    __shared__ float lw1[4096], lw2[4096], lpw[2048];
    __shared__ float lb1[64], lb2[64], lpb[32];
    const int b = blockIdx.x, tid = threadIdx.x;
    for (int idx = tid; idx < 4096; idx += 256) { lw1[idx] = w1[idx]; lw2[idx] = w2[idx]; }
    for (int idx = tid; idx < 2048; idx += 256) lpw[idx] = pw[idx];
    if (tid < 64) { lb1[tid] = b1[tid]; lb2[tid] = b2[tid]; }
    if (tid < 32) lpb[tid] = pb[tid];
    for (int idx = tid; idx < 2112; idx += 256) {
        float Av[9], Bb[9], s = 0.f;
        #pragma unroll
        for (int jj = 0; jj < 9; jj++) {
            size_t off = ((size_t)(b * 9 + jj)) * 2112 + idx;
            Av[jj] = A1[off];
            Bb[jj] = Bv1[off];
            s += lat1[off];
        }
        float m = 0.f;
        #pragma unroll
        for (int jj = 0; jj < 9; jj++) {
            float rowsum = 0.f;
            #pragma unroll
            for (int ii = 0; ii < 9; ii++) rowsum += fmaxf(Av[ii] + Bb[jj], 0.f);
            m += rowsum - fmaxf(Av[jj] + Bb[jj], 0.f);
        }
        ly[idx] = s + m * 0.125f;
    }
    __syncthreads();
    for (int idx = tid; idx < 2112; idx += 256) {
        int t = idx >> 6, d = idx & 63;
        float s = lb1[d];
        #pragma unroll 8
        for (int k = 0; k < 64; k++) s += ly[t * 64 + k] * lw1[k * 64 + d];
        lz[idx] = fmaxf(s, 0.f);
    }
    __syncthreads();
    for (int idx = tid; idx < 2112; idx += 256) {
        int t = idx >> 6, d = idx & 63;
        float s = lb2[d];
        #pragma unroll 8
        for (int k = 0; k < 64; k++) s += lz[t * 64 + k] * lw2[k * 64 + d];
        ly[idx] = s * (1.f / 9.f);
    }
    __syncthreads();
    for (int idx = tid; idx < 1056; idx += 256) {
        int e = idx / 33, t = idx - e * 33;
        float s = lpb[e];
        #pragma unroll 8
        for (int d = 0; d < 64; d++) s += ly[t * 64 + d] * lpw[d * 32 + e];
        out[(size_t)b * 1056 + idx] = s;
    }
}

// ---------------------------------------------------------------------------
extern "C" void kernel_launch(void* const* d_in, const int* in_sizes, int n_in,
                              void* d_out, int out_size, void* d_ws, size_t ws_size,
                              hipStream_t stream)
{
    const float* x = (const float*)d_in[0];
    const float* cw[6]; const float* cb[6]; const float* gg[6]; const float* gb[6];
    for (int l = 0; l < 6; l++) {
        cw[l] = (const float*)d_in[1 + 4 * l];
        cb[l] = (const float*)d_in[2 + 4 * l];
        gg[l] = (const float*)d_in[3 + 4 * l];
        gb[l] = (const float*)d_in[4 + 4 * l];
    }
    const float* ro_w = (const float*)d_in[25];
    const float* ro_b = (const float*)d_in[26];
    const float* mw0  = (const float*)d_in[27];
    const float* mb0  = (const float*)d_in[28];
    const float* mw1  = (const float*)d_in[29];
    const float* mb1  = (const float*)d_in[30];
    const float* rw1  = (const float*)d_in[31];
    const float* rb1  = (const float*)d_in[32];
    const float* rw2  = (const float*)d_in[33];
    const float* rb2  = (const float*)d_in[34];
    const float* pw   = (const float*)d_in[35];
    const float* pb   = (const float*)d_in[36];

    // ---- workspace (ws_size = 268,435,456 B measured; peak ~260.1 MB) ----
    // All activation buffers TRANSPOSED: [n][t][ci]. h1..h4 stay RAW
    // (pre-GN); the consuming conv applies GN+GELU in its staging path.
    // Layer 1 computes conv0 in-staging — NO h0gT buffer at all.
    char* ws = (char*)d_ws;
    bf16* h1T  = (bf16*)(ws);                 // [576][501][256] 147,750,912 B
    bf16* h2T  = (bf16*)(ws + 147750912);     // [576][251][256]
    bf16* h3T  = (bf16*)(ws + 221773824);     // [576][126][256] -> 258,932,736
    bf16* h4T  = (bf16*)(ws);                 // [576][64][256]  (h1T dead)
    bf16* h5T  = (bf16*)(ws + 147750912);     // [576][33][64]   (h2T dead)
    float* lat0 = (float*)(ws);               // 6 x 4,866,048 B (h4T dead after L5)
    float* A0   = lat0 + 1216512;
    float* Bv0  = A0   + 1216512;
    float* lat1 = Bv0  + 1216512;
    float* A1   = lat1 + 1216512;
    float* Bv1  = A1   + 1216512;
    float* stat  = (float*)(ws + 258932736);
    float* mu0   = stat;
    float* rstd0 = stat + 576;
    float* coef  = stat + 1152;               // 16
    float* ssumA = stat + 1168;               // 5 x 576
    float* ssqA  = ssumA + 5 * 576;
    float* w0taps = ssqA + 5 * 576;           // 768 f32 (conv0 tap planes)
    bf16*  Wp    = (bf16*)(ws + 258965504);   // 557,056 bf16 -> 260,079,616
    #define SSUM(l) (ssumA + ((l) - 1) * 576)
    #define SSQ(l)  (ssqA  + ((l) - 1) * 576)

    zero_k<<<(5760 + 255) / 256, 256, 0, stream>>>(ssumA, 2 * 5 * 576);
    wcvt_k<<<(557056 + 255) / 256, 256, 0, stream>>>(cw[1], cw[2], cw[3], cw[4], cw[5], Wp);
    m0red_k<<<1, 256, 0, stream>>>(cw[0], cb[0], coef, w0taps);
    c0stats_k<<<576, 256, 0, stream>>>(x, coef, mu0, rstd0);

    // ---- layer 1: conv0+GN0+GELU0 fused INTO the GEMM staging (MODE 2) ----
    convT_k<4, 4, 2><<<dim3(8, 576), 256, 0, stream>>>(
        nullptr, x, w0taps, Wp, cb[1], cb[0], h1T, SSUM(1), SSQ(1), 1000, 501, 0,
        mu0, rstd0, gg[0], gb[0], 0.f);

    // ---- layer 2: fused GN1+GELU on raw h1T during staging ----
    convT_k<4, 4, 1><<<dim3(4, 576), 256, 0, stream>>>(
        h1T, nullptr, nullptr, Wp + 131072, cb[2], nullptr, h2T, SSUM(2), SSQ(2), 501, 251, 0,
        SSUM(1), SSQ(1), gg[1], gb[1], 1.f / (256.f * 501.f));

    // ---- layer 3: fused GN2+GELU ----
    convT_k<4, 4, 1><<<dim3(2, 576), 256, 0, stream>>>(
        h2T, nullptr, nullptr, Wp + 262144, cb[3], nullptr, h3T, SSUM(3), SSQ(3), 251, 126, 0,
        SSUM(2), SSQ(2), gg[2], gb[2], 1.f / (256.f * 251.f));

    // ---- layer 4: fused GN3+GELU ----
    convT_k<4, 4, 1><<<dim3(1, 576), 256, 0, stream>>>(
        h3T, nullptr, nullptr, Wp + 393216, cb[4], nullptr, h4T, SSUM(4), SSQ(4), 126, 64, 0,
        SSUM(3), SSQ(3), gg[3], gb[3], 1.f / (256.f * 126.f));

    // ---- layer 5 (CO=64): fused GN4+GELU ----
    convT_k<3, 1, 1><<<dim3(1, 576), 256, 0, stream>>>(
        h4T, nullptr, nullptr, Wp + 524288, cb[5], nullptr, h5T, SSUM(5), SSQ(5), 64, 33, 0,
        SSUM(4), SSQ(4), gg[4], gb[4], 1.f / (256.f * 64.f));

    // ---- fused tail: readout+pre0 -> comb0+pre1 -> comb1+sum+MLP+proj ----
    readout_pre_k<<<576, 256, 0, stream>>>(h5T, ro_w, ro_b, gg[5], gb[5],
                                           SSUM(5), SSQ(5), 1.f / (64.f * 33.f),
                                           mw0, mb0, lat0, A0, Bv0);
    comb_pre_k<<<576, 256, 0, stream>>>(lat0, A0, Bv0, mw1, mb1, lat1, A1, Bv1);
    final2_k<<<64, 256, 0, stream>>>(lat1, A1, Bv1, rw1, rb1, rw2, rb2, pw, pb, (float*)d_out);
}

// Round 11
// 644.444 us; speedup vs baseline: 1.3957x; 1.0457x over previous
//
#include <hip/hip_runtime.h>
#include <hip/hip_bf16.h>

typedef __hip_bfloat16 bf16;
typedef __attribute__((ext_vector_type(8))) short s8v;   // 8 bf16 (16B)
typedef __attribute__((ext_vector_type(4))) float f4v;   // 4 f32 (C/D frag)

// Fast GELU (tanh form): x * sigmoid(1.595769x + 0.071355x^3).
// 6 VALU + 2 trans (v_exp, v_rcp) vs ~15+2 for the A&S-erf version.
// |gelu_tanh - gelu_erf| <= ~1e-3 absolute — ~60x under the 5.9e-2 check
// threshold after propagation through the GN-normalized conv stack.
__device__ __forceinline__ float gelu_f(float x) {
    float x2 = x * x;
    float z  = x * __builtin_fmaf(0.071355f, x2, 1.595769f);
    float e  = __expf(-z);
    return x * __builtin_amdgcn_rcpf(1.0f + e);
}
__device__ __forceinline__ unsigned short f2bf_u(float f) {
    bf16 b = __float2bfloat16(f);
    return *(unsigned short*)&b;
}
__device__ __forceinline__ float bfu2f(unsigned short u) {
    bf16 b = *(bf16*)&u;
    return __bfloat162float(b);
}

// ---------------------------------------------------------------------------
__global__ __launch_bounds__(256) void zero_k(float* __restrict__ p, int n) {
    int i = blockIdx.x * 256 + threadIdx.x;
    if (i < n) p[i] = 0.f;
}

// ---------------------------------------------------------------------------
// Convert + K-PERMUTE conv weights W1..W5 fp32 -> bf16.
// Wp[co][kc*64 + s*32 + ci_l] = W[co][kc*32+ci_l][s]  (kc<8, s<2, ci_l<32)
// ---------------------------------------------------------------------------
__global__ __launch_bounds__(256) void wcvt_k(
    const float* __restrict__ w1, const float* __restrict__ w2,
    const float* __restrict__ w3, const float* __restrict__ w4,
    const float* __restrict__ w5, bf16* __restrict__ dst)
{
    int i = blockIdx.x * 256 + threadIdx.x;
    if (i >= 557056) return;
    const float* src; int li;
    if      (i < 131072) { src = w1; li = i; }
    else if (i < 262144) { src = w2; li = i - 131072; }
    else if (i < 393216) { src = w3; li = i - 262144; }
    else if (i < 524288) { src = w4; li = i - 393216; }
    else                 { src = w5; li = i - 524288; }
    int co = li >> 9, rem = li & 511;
    int kc = rem >> 6, rr = rem & 63;
    int s = rr >> 5, cil = rr & 31;
    dst[i] = __float2bfloat16(src[co * 512 + (kc * 32 + cil) * 2 + s]);
}

// ---------------------------------------------------------------------------
// conv0 channel-collapse coefficients + conv0 TAP-PLANES w0t (f32):
// w0t[co] = W0[co][0], w0t[256+co] = W0[co][1], w0t[512+co] = W0[co][2].
// ---------------------------------------------------------------------------
__global__ __launch_bounds__(256) void m0red_k(
    const float* __restrict__ W0, const float* __restrict__ b0,
    float* __restrict__ coef, float* __restrict__ w0t)
{
    __shared__ float red[256];
    const int co = threadIdx.x;
    float w0 = W0[3 * co], w1 = W0[3 * co + 1], w2 = W0[3 * co + 2], b = b0[co];
    w0t[co] = w0; w0t[256 + co] = w1; w0t[512 + co] = w2;
    float vals[14] = {w0, w1, w2, b,
                      w0 * w0, w1 * w1, w2 * w2, b * b,
                      2.f * w0 * w1, 2.f * w0 * w2, 2.f * w1 * w2,
                      2.f * w0 * b, 2.f * w1 * b, 2.f * w2 * b};
    for (int k = 0; k < 14; k++) {
        red[co] = vals[k];
        __syncthreads();
        for (int st = 128; st > 0; st >>= 1) {
            if (co < st) red[co] += red[co + st];
            __syncthreads();
        }
        if (co == 0) coef[k] = red[0];
        __syncthreads();
    }
}

// ---------------------------------------------------------------------------
// GN0 stats per node via the collapsed quadratic form. One block per node.
// ---------------------------------------------------------------------------
__global__ __launch_bounds__(256) void c0stats_k(
    const float* __restrict__ x, const float* __restrict__ coef,
    float* __restrict__ mu0, float* __restrict__ rstd0)
{
    __shared__ float xsl[3008];
    __shared__ float red[512];
    const int n = blockIdx.x, tid = threadIdx.x;
    const float* xr = x + (size_t)n * 3000;
    for (int i = tid; i < 750; i += 256) *(float4*)&xsl[4 + 4 * i] = *(const float4*)(xr + 4 * i);
    if (tid < 4) xsl[tid] = 0.f;
    float c[14];
    #pragma unroll
    for (int k = 0; k < 14; k++) c[k] = coef[k];
    __syncthreads();
    float S = 0.f, Q = 0.f;
    if (tid < 250) {
        float f[16];
        #pragma unroll
        for (int k = 0; k < 4; k++) *(float4*)&f[4 * k] = *(const float4*)&xsl[12 * tid + 4 * k];
        #pragma unroll
        for (int j = 0; j < 4; j++) {
            float x0 = f[3 * j + 3], x1 = f[3 * j + 4], x2 = f[3 * j + 5];
            S += c[0] * x0 + c[1] * x1 + c[2] * x2 + c[3];
            Q += c[4] * x0 * x0 + c[5] * x1 * x1 + c[6] * x2 * x2 + c[7]
               + c[8] * x0 * x1 + c[9] * x0 * x2 + c[10] * x1 * x2
               + c[11] * x0 + c[12] * x1 + c[13] * x2;
        }
    }
    red[tid] = S; red[256 + tid] = Q;
    __syncthreads();
    for (int st = 128; st > 0; st >>= 1) {
        if (tid < st) { red[tid] += red[tid + st]; red[256 + tid] += red[256 + tid + st]; }
        __syncthreads();
    }
    if (tid == 0) {
        float m = red[0] * (1.f / 256000.f);
        float var = red[256] * (1.f / 256000.f) - m * m;
        mu0[n] = m;
        rstd0[n] = rsqrtf(var + 1e-5f);
    }
}

// ===========================================================================
// Hybrid MFMA conv GEMM — R9/R10 structure (single swizzled LDS A tile,
// serial stage -> B-loads -> barrier -> MFMA(setprio 1) -> barrier).
// MODE 1: A input is RAW prev-conv output; staging applies GN+GELU.
// MODE 2 (layer 1): A computed in-place from x: conv0 (width-3, 1->256ch)
//   + GN0 + GELU0 via LDS-staged x window + w0 tap planes. No h0gT buffer.
// ===========================================================================
template<int MW, int NW, int MODE>
__global__ __launch_bounds__(256) void convT_k(
    const bf16* __restrict__ g, const float* __restrict__ xraw,
    const float* __restrict__ w0t, const bf16* __restrict__ Wp,
    const float* __restrict__ bias, const float* __restrict__ b0c,
    bf16* __restrict__ hout, float* __restrict__ ssum, float* __restrict__ ssq,
    int T_g, int T_out, int n0,
    const float* __restrict__ pssum, const float* __restrict__ pssq,
    const float* __restrict__ pgam, const float* __restrict__ pbet,
    float pinvCT)
{
    constexpr int CO = 4 * NW * 16;
    constexpr int MT = MW * 16;
    constexpr int NSLOT = MT * 8;          // 16B slots in the A tile
    constexpr int NU = (NSLOT + 255) / 256;
    __shared__ bf16 aT[MT * 64];           // single swizzled A tile
    __shared__ float biasS[CO];
    __shared__ float red[512];
    __shared__ float acoS[256], ccoS[256];
    __shared__ float xs[(MODE == 2) ? 400 : 1];    // x window (MODE 2)
    __shared__ float w0s[(MODE == 2) ? 768 : 1];   // conv0 tap planes (MODE 2)
    const int n  = blockIdx.y;
    const int t0 = blockIdx.x * MT;
    const int tid = threadIdx.x;
    for (int i = tid; i < CO; i += 256) biasS[i] = bias[i];
    if (MODE == 1) {
        float mu = pssum[n0 + n] * pinvCT;
        float rs = rsqrtf(pssq[n0 + n] * pinvCT - mu * mu + 1e-5f);
        float a = rs * pgam[tid];
        acoS[tid] = a;
        ccoS[tid] = pbet[tid] - mu * a;
        __syncthreads();               // coefs visible to staging below
    } else { // MODE 2
        float mu = pssum[n];           // mu0[n]
        float rs = pssq[n];            // rstd0[n]
        float a = rs * pgam[tid];
        acoS[tid] = a;
        ccoS[tid] = (b0c[tid] - mu) * a + pbet[tid];
        for (int i = tid; i < 768; i += 256) w0s[i] = w0t[i];
        const float* xr = xraw + (size_t)n * 3000;
        for (int i = tid; i < 400; i += 256) {
            int xg = 6 * t0 - 4 + i;
            xs[i] = ((unsigned)xg < 3000u) ? xr[xg] : 0.f;
        }
        __syncthreads();
    }
    const int w = tid >> 6, lane = tid & 63;
    const int l16 = lane & 15, quad = lane >> 4;
    const int sx = l16 & 7;                // read-side swizzle key (row & 7)
    const bf16* gb = (MODE == 2) ? nullptr : (g + (size_t)n * T_g * 256);

    // Per-thread staging slot geometry (kc-independent).
    // s_inv: thread's u-th slot doesn't exist (only when NSLOT%256!=0).
    // s_tin==-1 (left pad) / >=T_g (right pad) are VALID slots staging zeros.
    bool s_inv[NU];
    int s_q[NU], s_tin[NU], s_off[NU];
    #pragma unroll
    for (int u = 0; u < NU; u++) {
        int slot = tid + 256 * u;
        s_inv[u] = (NSLOT % 256 != 0) && (slot >= NSLOT);
        if (s_inv[u]) { s_tin[u] = 0x7fffffff; s_q[u] = 0; s_off[u] = 0; continue; }
        int t = slot >> 3, j = slot & 7;
        int ks = j >> 2, q = j & 3;
        s_q[u] = q;
        s_tin[u] = 2 * (t0 + t) - 1 + ks;
        s_off[u] = (t * 8 + (j ^ (t & 7))) * 8;   // swizzled LDS elem offset
    }

    f4v acc[MW][NW];
    #pragma unroll
    for (int i = 0; i < MW; i++)
        #pragma unroll
        for (int j = 0; j < NW; j++) acc[i][j] = (f4v){0.f, 0.f, 0.f, 0.f};

    for (int kc = 0; kc < 8; kc++) {
        // ---- stage A tile (serial phase between barriers)
        #pragma unroll
        for (int u = 0; u < NU; u++) {
            if (s_inv[u]) continue;
            int tin = s_tin[u];
            s8v v = (s8v){0, 0, 0, 0, 0, 0, 0, 0};
            if ((unsigned)tin < (unsigned)T_g) {
                const int ci0 = kc * 32 + s_q[u] * 8;
                float4 a0 = *(const float4*)&acoS[ci0], a1 = *(const float4*)&acoS[ci0 + 4];
                float4 c0 = *(const float4*)&ccoS[ci0], c1 = *(const float4*)&ccoS[ci0 + 4];
                float av[8] = {a0.x, a0.y, a0.z, a0.w, a1.x, a1.y, a1.z, a1.w};
                float cv[8] = {c0.x, c0.y, c0.z, c0.w, c1.x, c1.y, c1.z, c1.w};
                unsigned short* uu = (unsigned short*)&v;
                if (MODE == 2) {
                    // conv0 from x window + GN0 + GELU0
                    int lx = 3 * (tin - 2 * t0) + 3;   // index of x[3*tin-1] in xs
                    float x0 = xs[lx], x1 = xs[lx + 1], x2 = xs[lx + 2];
                    float4 wa0 = *(const float4*)&w0s[ci0],       wa1 = *(const float4*)&w0s[ci0 + 4];
                    float4 wb0 = *(const float4*)&w0s[256 + ci0], wb1 = *(const float4*)&w0s[256 + ci0 + 4];
                    float4 wc0 = *(const float4*)&w0s[512 + ci0], wc1 = *(const float4*)&w0s[512 + ci0 + 4];
                    float wav[8] = {wa0.x, wa0.y, wa0.z, wa0.w, wa1.x, wa1.y, wa1.z, wa1.w};
                    float wbv[8] = {wb0.x, wb0.y, wb0.z, wb0.w, wb1.x, wb1.y, wb1.z, wb1.w};
                    float wcv[8] = {wc0.x, wc0.y, wc0.z, wc0.w, wc1.x, wc1.y, wc1.z, wc1.w};
                    #pragma unroll
                    for (int jj = 0; jj < 8; jj++) {
                        float conv = wav[jj] * x0 + wbv[jj] * x1 + wcv[jj] * x2;
                        uu[jj] = f2bf_u(gelu_f(conv * av[jj] + cv[jj]));
                    }
                } else {
                    // load raw prev-conv output + GN + GELU
                    v = *(const s8v*)(gb + (size_t)tin * 256 + ci0);
                    #pragma unroll
                    for (int jj = 0; jj < 8; jj++)
                        uu[jj] = f2bf_u(gelu_f(bfu2f(uu[jj]) * av[jj] + cv[jj]));
                }
            }
            *(s8v*)&aT[s_off[u]] = v;
        }
        // ---- B fragments direct from global (independent of LDS)
        s8v bfr[2][NW];
        #pragma unroll
        for (int ks = 0; ks < 2; ks++)
            #pragma unroll
            for (int j = 0; j < NW; j++) {
                int co = w * NW * 16 + j * 16 + l16;
                bfr[ks][j] = *(const s8v*)(Wp + (size_t)co * 512 + kc * 64 + ks * 32 + quad * 8);
            }
        __syncthreads();
        // ---- ds_read + MFMA (T5: bias the CU scheduler toward this wave)
        __builtin_amdgcn_s_setprio(1);
        #pragma unroll
        for (int ks = 0; ks < 2; ks++) {
            const int sl = (ks * 4 + quad) ^ sx;   // swizzled 16B slot
            s8v af[MW];
            #pragma unroll
            for (int i = 0; i < MW; i++)
                af[i] = *(const s8v*)&aT[(i * 16 + l16) * 64 + sl * 8];
            #pragma unroll
            for (int i = 0; i < MW; i++)
                #pragma unroll
                for (int j = 0; j < NW; j++)
                    acc[i][j] = __builtin_amdgcn_mfma_f32_16x16x32_bf16(af[i], bfr[ks][j], acc[i][j], 0, 0, 0);
        }
        __builtin_amdgcn_s_setprio(0);
        __syncthreads();
    }

    float lsum = 0.f, lsq = 0.f;
    #pragma unroll
    for (int i = 0; i < MW; i++) {
        #pragma unroll
        for (int r = 0; r < 4; r++) {
            int t = t0 + i * 16 + quad * 4 + r;
            if (t < T_out) {
                bf16* orow = hout + ((size_t)n * T_out + t) * CO;
                #pragma unroll
                for (int j = 0; j < NW; j++) {
                    int co = w * NW * 16 + j * 16 + l16;
                    float v = acc[i][j][r] + biasS[co];
                    orow[co] = __float2bfloat16(v);
                    lsum += v; lsq += v * v;
                }
            }
        }
    }
    red[tid] = lsum; red[256 + tid] = lsq;
    __syncthreads();
    for (int st = 128; st > 0; st >>= 1) {
        if (tid < st) { red[tid] += red[tid + st]; red[256 + tid] += red[256 + tid + st]; }
        __syncthreads();
    }
    if (tid == 0) { atomicAdd(&ssum[n0 + n], red[0]); atomicAdd(&ssq[n0 + n], red[256]); }
}

// ---------------------------------------------------------------------------
// Tail kernel 1: GN5+GELU on h5T[n][t][c] + readout 1x1 + msg round-0 pre.
// ---------------------------------------------------------------------------
__global__ __launch_bounds__(256) void readout_pre_k(
    const bf16* __restrict__ h5T, const float* __restrict__ row,
    const float* __restrict__ rob, const float* __restrict__ g5,
    const float* __restrict__ be5, const float* __restrict__ ssum,
    const float* __restrict__ ssq, float invCT,
    const float* __restrict__ mw, const float* __restrict__ mb,
    float* __restrict__ lat0, float* __restrict__ A0, float* __restrict__ Bv0)
{
    __shared__ float lh[2112];   // [t][c] 33 x 64
    __shared__ float ll[2112];   // lat [t][d]
    __shared__ float lw[8192];
    __shared__ float lb[64];
    const int n = blockIdx.x, tid = threadIdx.x;
    const float mu = ssum[n] * invCT;
    const float rs = rsqrtf(ssq[n] * invCT - mu * mu + 1e-5f);
    for (int idx = tid; idx < 2112; idx += 256) {
        int c = idx & 63;
        float a = rs * g5[c];
        float v = __bfloat162float(h5T[(size_t)n * 2112 + idx]) * a + (be5[c] - mu * a);
        lh[idx] = gelu_f(v);
    }
    for (int idx = tid; idx < 4096; idx += 256) lw[idx] = row[idx];
    if (tid < 64) lb[tid] = rob[tid];
    __syncthreads();
    for (int idx = tid; idx < 2112; idx += 256) {
        int t = idx >> 6, d = idx & 63;
        float a = lb[d];
        #pragma unroll 8
        for (int c = 0; c < 64; c++) a += lh[t * 64 + c] * lw[c * 64 + d];
        ll[idx] = a;
        lat0[(size_t)n * 2112 + idx] = a;
    }
    __syncthreads();
    for (int idx = tid; idx < 8192; idx += 256) lw[idx] = mw[idx];
    if (tid < 64) lb[tid] = mb[tid];
    __syncthreads();
    for (int idx = tid; idx < 2112; idx += 256) {
        int t = idx >> 6, d = idx & 63;
        float a = 0.f, bb = lb[d];
        #pragma unroll 8
        for (int k = 0; k < 64; k++) {
            float xv = ll[t * 64 + k];
            a  += xv * lw[k * 64 + d];
            bb += xv * lw[(64 + k) * 64 + d];
        }
        A0[(size_t)n * 2112 + idx]  = a;
        Bv0[(size_t)n * 2112 + idx] = bb;
    }
}

// ---------------------------------------------------------------------------
// Tail kernel 2: msg round-0 combine + msg round-1 pre.
// ---------------------------------------------------------------------------
__global__ __launch_bounds__(256) void comb_pre_k(
    const float* __restrict__ lat0, const float* __restrict__ A0,
    const float* __restrict__ Bv0, const float* __restrict__ mw,
    const float* __restrict__ mb, float* __restrict__ lat1,
    float* __restrict__ A1, float* __restrict__ Bv1)
{
    __shared__ float ll[2112];
    __shared__ float lw[8192];
    __shared__ float lb[64];
    const int n = blockIdx.x, tid = threadIdx.x;
    const int b9 = (n / 9) * 9, j = n - b9;
    for (int idx = tid; idx < 2112; idx += 256) {
        float base = Bv0[(size_t)n * 2112 + idx];
        float s = 0.f;
        #pragma unroll
        for (int i = 0; i < 9; i++) {
            if (i == j) continue;
            s += fmaxf(A0[(size_t)(b9 + i) * 2112 + idx] + base, 0.f);
        }
        float v = lat0[(size_t)n * 2112 + idx] + s * 0.125f;
        ll[idx] = v;
        lat1[(size_t)n * 2112 + idx] = v;
    }
    for (int idx = tid; idx < 8192; idx += 256) lw[idx] = mw[idx];
    if (tid < 64) lb[tid] = mb[tid];
    __syncthreads();
    for (int idx = tid; idx < 2112; idx += 256) {
        int t = idx >> 6, d = idx & 63;
        float a = 0.f, bb = lb[d];
        #pragma unroll 8
        for (int k = 0; k < 64; k++) {
            float xv = ll[t * 64 + k];
            a  += xv * lw[k * 64 + d];
            bb += xv * lw[(64 + k) * 64 + d];
        }
        A1[(size_t)n * 2112 + idx]  = a;
        Bv1[(size_t)n * 2112 + idx] = bb;
    }
}

// ---------------------------------------------------------------------------
// Tail kernel 3: msg round-1 combine + view-sum + readout MLP + projection.
// ---------------------------------------------------------------------------
__global__ __launch_bounds__(256) void final2_k(
    const float* __restrict__ lat1, const float* __restrict__ A1,
    const float* __restrict__ Bv1,
    const float* __restrict__ w1, const float* __restrict__ b1,
    const float* __restrict__ w2, const float* __restrict__ b2,
    const float* __restrict__ pw, const float* __restrict__ pb,
    float* __restrict__ out)
{
    __shared__ float ly[2112], lz[2112];
    __shared__ float lw1[4096], lw2[4096], lpw[2048];
    __shared__ float lb1[64], lb2[64], lpb[32];
    const int b = blockIdx.x, tid = threadIdx.x;
    for (int idx = tid; idx < 4096; idx += 256) { lw1[idx] = w1[idx]; lw2[idx] = w2[idx]; }
    for (int idx = tid; idx < 2048; idx += 256) lpw[idx] = pw[idx];
    if (tid < 64) { lb1[tid] = b1[tid]; lb2[tid] = b2[tid]; }
    if (tid < 32) lpb[tid] = pb[tid];
    for (int idx = tid; idx < 2112; idx += 256) {
        float Av[9], Bb[9], s = 0.f;
        #pragma unroll
        for (int jj = 0; jj < 9; jj++) {
            size_t off = ((size_t)(b * 9 + jj)) * 2112 + idx;
            Av[jj] = A1[off];
            Bb[jj] = Bv1[off];
            s += lat1[off];
        }
        float m = 0.f;
        #pragma unroll
        for (int jj = 0; jj < 9; jj++) {
            float rowsum = 0.f;
            #pragma unroll
            for (int ii = 0; ii < 9; ii++) rowsum += fmaxf(Av[ii] + Bb[jj], 0.f);
            m += rowsum - fmaxf(Av[jj] + Bb[jj], 0.f);
        }
        ly[idx] = s + m * 0.125f;
    }
    __syncthreads();
    for (int idx = tid; idx < 2112; idx += 256) {
        int t = idx >> 6, d = idx & 63;
        float s = lb1[d];
        #pragma unroll 8
        for (int k = 0; k < 64; k++) s += ly[t * 64 + k] * lw1[k * 64 + d];
        lz[idx] = fmaxf(s, 0.f);
    }
    __syncthreads();
    for (int idx = tid; idx < 2112; idx += 256) {
        int t = idx >> 6, d = idx & 63;
        float s = lb2[d];
        #pragma unroll 8
        for (int k = 0; k < 64; k++) s += lz[t * 64 + k] * lw2[k * 64 + d];
        ly[idx] = s * (1.f / 9.f);
    }
    __syncthreads();
    for (int idx = tid; idx < 1056; idx += 256) {
        int e = idx / 33, t = idx - e * 33;
        float s = lpb[e];
        #pragma unroll 8
        for (int d = 0; d < 64; d++) s += ly[t * 64 + d] * lpw[d * 32 + e];
        out[(size_t)b * 1056 + idx] = s;
    }
}

// ---------------------------------------------------------------------------
extern "C" void kernel_launch(void* const* d_in, const int* in_sizes, int n_in,
                              void* d_out, int out_size, void* d_ws, size_t ws_size,
                              hipStream_t stream)
{
    const float* x = (const float*)d_in[0];
    const float* cw[6]; const float* cb[6]; const float* gg[6]; const float* gb[6];
    for (int l = 0; l < 6; l++) {
        cw[l] = (const float*)d_in[1 + 4 * l];
        cb[l] = (const float*)d_in[2 + 4 * l];
        gg[l] = (const float*)d_in[3 + 4 * l];
        gb[l] = (const float*)d_in[4 + 4 * l];
    }
    const float* ro_w = (const float*)d_in[25];
    const float* ro_b = (const float*)d_in[26];
    const float* mw0  = (const float*)d_in[27];
    const float* mb0  = (const float*)d_in[28];
    const float* mw1  = (const float*)d_in[29];
    const float* mb1  = (const float*)d_in[30];
    const float* rw1  = (const float*)d_in[31];
    const float* rb1  = (const float*)d_in[32];
    const float* rw2  = (const float*)d_in[33];
    const float* rb2  = (const float*)d_in[34];
    const float* pw   = (const float*)d_in[35];
    const float* pb   = (const float*)d_in[36];

    // ---- workspace (ws_size = 268,435,456 B measured; peak ~260.1 MB) ----
    // All activation buffers TRANSPOSED: [n][t][ci]. h1..h4 stay RAW
    // (pre-GN); the consuming conv applies GN+GELU in its staging path.
    // Layer 1 computes conv0 in-staging — NO h0gT buffer at all.
    char* ws = (char*)d_ws;
    bf16* h1T  = (bf16*)(ws);                 // [576][501][256] 147,750,912 B
    bf16* h2T  = (bf16*)(ws + 147750912);     // [576][251][256]
    bf16* h3T  = (bf16*)(ws + 221773824);     // [576][126][256] -> 258,932,736
    bf16* h4T  = (bf16*)(ws);                 // [576][64][256]  (h1T dead)
    bf16* h5T  = (bf16*)(ws + 147750912);     // [576][33][64]   (h2T dead)
    float* lat0 = (float*)(ws);               // 6 x 4,866,048 B (h4T dead after L5)
    float* A0   = lat0 + 1216512;
    float* Bv0  = A0   + 1216512;
    float* lat1 = Bv0  + 1216512;
    float* A1   = lat1 + 1216512;
    float* Bv1  = A1   + 1216512;
    float* stat  = (float*)(ws + 258932736);
    float* mu0   = stat;
    float* rstd0 = stat + 576;
    float* coef  = stat + 1152;               // 16
    float* ssumA = stat + 1168;               // 5 x 576
    float* ssqA  = ssumA + 5 * 576;
    float* w0taps = ssqA + 5 * 576;           // 768 f32 (conv0 tap planes)
    bf16*  Wp    = (bf16*)(ws + 258965504);   // 557,056 bf16 -> 260,079,616
    #define SSUM(l) (ssumA + ((l) - 1) * 576)
    #define SSQ(l)  (ssqA  + ((l) - 1) * 576)

    zero_k<<<(5760 + 255) / 256, 256, 0, stream>>>(ssumA, 2 * 5 * 576);
    wcvt_k<<<(557056 + 255) / 256, 256, 0, stream>>>(cw[1], cw[2], cw[3], cw[4], cw[5], Wp);
    m0red_k<<<1, 256, 0, stream>>>(cw[0], cb[0], coef, w0taps);
    c0stats_k<<<576, 256, 0, stream>>>(x, coef, mu0, rstd0);

    // ---- layer 1: conv0+GN0+GELU0 fused INTO the GEMM staging (MODE 2) ----
    convT_k<4, 4, 2><<<dim3(8, 576), 256, 0, stream>>>(
        nullptr, x, w0taps, Wp, cb[1], cb[0], h1T, SSUM(1), SSQ(1), 1000, 501, 0,
        mu0, rstd0, gg[0], gb[0], 0.f);

    // ---- layer 2: fused GN1+GELU on raw h1T during staging ----
    convT_k<4, 4, 1><<<dim3(4, 576), 256, 0, stream>>>(
        h1T, nullptr, nullptr, Wp + 131072, cb[2], nullptr, h2T, SSUM(2), SSQ(2), 501, 251, 0,
        SSUM(1), SSQ(1), gg[1], gb[1], 1.f / (256.f * 501.f));

    // ---- layer 3: fused GN2+GELU ----
    convT_k<4, 4, 1><<<dim3(2, 576), 256, 0, stream>>>(
        h2T, nullptr, nullptr, Wp + 262144, cb[3], nullptr, h3T, SSUM(3), SSQ(3), 251, 126, 0,
        SSUM(2), SSQ(2), gg[2], gb[2], 1.f / (256.f * 251.f));

    // ---- layer 4: fused GN3+GELU ----
    convT_k<4, 4, 1><<<dim3(1, 576), 256, 0, stream>>>(
        h3T, nullptr, nullptr, Wp + 393216, cb[4], nullptr, h4T, SSUM(4), SSQ(4), 126, 64, 0,
        SSUM(3), SSQ(3), gg[3], gb[3], 1.f / (256.f * 126.f));

    // ---- layer 5 (CO=64): fused GN4+GELU ----
    convT_k<3, 1, 1><<<dim3(1, 576), 256, 0, stream>>>(
        h4T, nullptr, nullptr, Wp + 524288, cb[5], nullptr, h5T, SSUM(5), SSQ(5), 64, 33, 0,
        SSUM(4), SSQ(4), gg[4], gb[4], 1.f / (256.f * 64.f));

    // ---- fused tail: readout+pre0 -> comb0+pre1 -> comb1+sum+MLP+proj ----
    readout_pre_k<<<576, 256, 0, stream>>>(h5T, ro_w, ro_b, gg[5], gb[5],
                                           SSUM(5), SSQ(5), 1.f / (64.f * 33.f),
                                           mw0, mb0, lat0, A0, Bv0);
    comb_pre_k<<<576, 256, 0, stream>>>(lat0, A0, Bv0, mw1, mb1, lat1, A1, Bv1);
    final2_k<<<64, 256, 0, stream>>>(lat1, A1, Bv1, rw1, rb1, rw2, rb2, pw, pb, (float*)d_out);
}